// Round 18
// baseline (1037.206 us; speedup 1.0000x reference)
//
#include <hip/hip_runtime.h>
#include <hip/hip_bf16.h>

typedef __hip_bfloat16 bf16;

#define N_NODES 100000
#define N_EDGES 400000
#define EO_MIN  100000   // tier-0 fallback only

// ---- f32 geometry of d_out (proven r12-r16) ----
#define OUT_E_ELEM ((size_t)N_NODES*128)
#define SCORES_B   ((size_t)N_EDGES*8*4)            // 12.8 MB
#define SEG_B      ((size_t)N_NODES*8*4)            //  3.2 MB
#define AGG_BYTES  ((size_t)N_NODES*128*4)          // 51.2 MB
#define WSW_OFF    (SCORES_B + 2*SEG_B)             // fallback wsw inside d_out

// prepped-weight tables (shorts): WT[n][k] transposed, hi then lo.
#define WT_SZ   16384
#define OFF_WQ  (0*WT_SZ)
#define OFF_WK  (2*WT_SZ)
#define OFF_WEW (4*WT_SZ)
#define OFF_WEB (6*WT_SZ)
#define OFF_WEO (8*WT_SZ)
#define OFF_WV  (10*WT_SZ)
#define OFF_WEV (12*WT_SZ)
#define OFF_WA  (14*WT_SZ)    // 16x128 padded, hi + lo(+2048)
#define WSW_SHORTS (14*WT_SZ + 2*2048)
#define WSW_BYTES  ((size_t)WSW_SHORTS*2)

using short8 = __attribute__((ext_vector_type(8))) short;
using f32x4  = __attribute__((ext_vector_type(4))) float;

__device__ __forceinline__ float b2f(bf16 v){ return __bfloat162float(v); }
__device__ __forceinline__ bf16  f2b(float v){ return __float2bfloat16(v); }
__device__ __forceinline__ short bits(bf16 v){ short s; __builtin_memcpy(&s, &v, 2); return s; }
__device__ __forceinline__ void split(float v, short& h, short& l){
  bf16 hb = f2b(v);
  h = bits(hb);
  l = bits(f2b(v - b2f(hb)));
}
__device__ __forceinline__ float san(float v){
  return (v == v && fabsf(v) < 1e30f) ? v : 0.f;
}
__device__ __forceinline__ unsigned fmap(float f){
  unsigned u = __float_as_uint(f);
  return (u & 0x80000000u) ? ~u : (u | 0x80000000u);
}
__device__ __forceinline__ float funmap(unsigned u){
  unsigned b = (u & 0x80000000u) ? (u ^ 0x80000000u) : ~u;
  return __uint_as_float(b);
}

// ---- unified weight prep (r16-proven)
__global__ void prep_v18(const float* __restrict__ W_Q, const float* __restrict__ W_K,
                         const float* __restrict__ W_Ew, const float* __restrict__ W_Eb,
                         const float* __restrict__ W_Eo, const float* __restrict__ W_V,
                         const float* __restrict__ W_Ev, const float* __restrict__ W_A,
                         short* __restrict__ wsw)
{
  const int b = blockIdx.x;
  if (b < 896){
    const int mi = b >> 7, n = b & 127;
    const float* W = (mi==0)?W_Q:(mi==1)?W_K:(mi==2)?W_Ew:(mi==3)?W_Eb:(mi==4)?W_Eo:(mi==5)?W_V:W_Ev;
    short* dh = wsw + mi*2*WT_SZ;
    short* dl = dh + WT_SZ;
    for (int k = threadIdx.x; k < 128; k += 128){
      short h, l; split(W[(size_t)k*128 + n], h, l);
      dh[n*128 + k] = h; dl[n*128 + k] = l;
    }
  } else {
    const int n = b - 896;
    short* dh = wsw + OFF_WA;
    short* dl = dh + 2048;
    for (int k = threadIdx.x; k < 128; k += 128){
      float v = (n < 8) ? W_A[(size_t)k*8 + n] : 0.f;
      short h, l; split(v, h, l);
      dh[n*128 + k] = h; dl[n*128 + k] = l;
    }
  }
}

__device__ __forceinline__ void stage_row(const float* __restrict__ src,
                                          short* __restrict__ dh, short* __restrict__ dl){
  const float4 v0 = *reinterpret_cast<const float4*>(src);
  const float4 v1 = *reinterpret_cast<const float4*>(src + 4);
  const float vv[8] = {v0.x, v0.y, v0.z, v0.w, v1.x, v1.y, v1.z, v1.w};
  short8 h, l;
  #pragma unroll
  for (int q = 0; q < 8; ++q){ short hh, ll; split(vv[q], hh, ll); h[q] = hh; l[q] = ll; }
  *reinterpret_cast<short8*>(dh) = h;
  *reinterpret_cast<short8*>(dl) = l;
}

// ---- nodeproj (r15/r16-proven)
__global__ __launch_bounds__(256) void nodeproj_v18(
    const float* __restrict__ x, const short* __restrict__ wsw,
    const float* __restrict__ b_Q, const float* __restrict__ b_K,
    const float* __restrict__ b_V,
    float* __restrict__ Qn, float* __restrict__ Kn, float* __restrict__ Vn,
    int do_v)
{
  __shared__ __align__(16) short Xh[2][2048], Xl[2][2048];
  const int tid = threadIdx.x;
  const int n0  = blockIdx.x * 32;

  {
    const int r = tid & 15, c = tid >> 4;
    #pragma unroll
    for (int rg = 0; rg < 2; ++rg)
      stage_row(x + (size_t)(n0 + rg*16 + r)*128 + c*8,
                &Xh[rg][(c*16 + r)*8], &Xl[rg][(c*16 + r)*8]);
  }
  __syncthreads();

  const int wv = tid >> 6;
  const int mi = (tid & 63) & 15;
  const int kg = (tid & 63) >> 4;

  f32x4 aQ[2][2], aK[2][2], aV[2][2];
  #pragma unroll
  for (int rg = 0; rg < 2; ++rg)
    #pragma unroll
    for (int t = 0; t < 2; ++t){
      aQ[rg][t] = (f32x4){0,0,0,0}; aK[rg][t] = (f32x4){0,0,0,0}; aV[rg][t] = (f32x4){0,0,0,0};
    }

  #pragma unroll
  for (int ks = 0; ks < 4; ++ks){
    const int ao = ((ks*4 + kg)*16 + mi)*8;
    const int kb = ks*32 + kg*8;
    short8 xh[2], xl[2];
    #pragma unroll
    for (int rg = 0; rg < 2; ++rg){
      xh[rg] = *reinterpret_cast<const short8*>(&Xh[rg][ao]);
      xl[rg] = *reinterpret_cast<const short8*>(&Xl[rg][ao]);
    }
    #pragma unroll
    for (int t = 0; t < 2; ++t){
      const int n = (wv*2 + t)*16 + mi;
      const short8 qh = *reinterpret_cast<const short8*>(&wsw[OFF_WQ + n*128 + kb]);
      const short8 ql = *reinterpret_cast<const short8*>(&wsw[OFF_WQ + WT_SZ + n*128 + kb]);
      const short8 kh = *reinterpret_cast<const short8*>(&wsw[OFF_WK + n*128 + kb]);
      const short8 kl = *reinterpret_cast<const short8*>(&wsw[OFF_WK + WT_SZ + n*128 + kb]);
      const short8 vh = *reinterpret_cast<const short8*>(&wsw[OFF_WV + n*128 + kb]);
      const short8 vl = *reinterpret_cast<const short8*>(&wsw[OFF_WV + WT_SZ + n*128 + kb]);
      #pragma unroll
      for (int rg = 0; rg < 2; ++rg){
        aQ[rg][t] = __builtin_amdgcn_mfma_f32_16x16x32_bf16(xh[rg], qh, aQ[rg][t], 0,0,0);
        aK[rg][t] = __builtin_amdgcn_mfma_f32_16x16x32_bf16(xh[rg], kh, aK[rg][t], 0,0,0);
        aQ[rg][t] = __builtin_amdgcn_mfma_f32_16x16x32_bf16(xl[rg], qh, aQ[rg][t], 0,0,0);
        aK[rg][t] = __builtin_amdgcn_mfma_f32_16x16x32_bf16(xl[rg], kh, aK[rg][t], 0,0,0);
        aQ[rg][t] = __builtin_amdgcn_mfma_f32_16x16x32_bf16(xh[rg], ql, aQ[rg][t], 0,0,0);
        aK[rg][t] = __builtin_amdgcn_mfma_f32_16x16x32_bf16(xh[rg], kl, aK[rg][t], 0,0,0);
        if (do_v){
          aV[rg][t] = __builtin_amdgcn_mfma_f32_16x16x32_bf16(xh[rg], vh, aV[rg][t], 0,0,0);
          aV[rg][t] = __builtin_amdgcn_mfma_f32_16x16x32_bf16(xl[rg], vh, aV[rg][t], 0,0,0);
          aV[rg][t] = __builtin_amdgcn_mfma_f32_16x16x32_bf16(xh[rg], vl, aV[rg][t], 0,0,0);
        }
      }
    }
  }

  #pragma unroll
  for (int rg = 0; rg < 2; ++rg)
    #pragma unroll
    for (int t = 0; t < 2; ++t){
      const int n = (wv*2 + t)*16 + mi;
      const float bq = b_Q[n], bk = b_K[n], bv = b_V[n];
      #pragma unroll
      for (int q = 0; q < 4; ++q){
        const size_t row = n0 + rg*16 + kg*4 + q;
        Qn[row*128 + n] = aQ[rg][t][q] + bq;
        Kn[row*128 + n] = aK[rg][t][q] + bk;
        if (do_v) Vn[row*128 + n] = aV[rg][t][q] + bv;
      }
    }
}

// ---- MFMA front v18 (r17 body): LDS time-multiplexed {ea-frags -> qk -> af-frags}
__global__ __launch_bounds__(256) void front_qk_v18(
    const float* __restrict__ ea, const int* __restrict__ eidx,
    const float* __restrict__ Qn, const float* __restrict__ Kn,
    const float* __restrict__ b_Ew, const float* __restrict__ b_Eb,
    const float* __restrict__ b_A,  const float* __restrict__ b_Eo,
    const short* __restrict__ wsw,
    float* __restrict__ scores, unsigned* __restrict__ segmax,
    float* __restrict__ oute, int do_score)
{
  __shared__ __align__(16) char smem[16384];
  __shared__ int sIdx[32], tIdx[32];
  short* AFh = (short*)smem;            // [2][2048]
  short* AFl = (short*)(smem + 8192);   // [2][2048]
  float* qkf = (float*)smem;            // [32][128] (aliases AFh/AFl)

  const int tid = threadIdx.x;
  const int e0  = blockIdx.x * 32;

  if (tid < 32){
    sIdx[tid] = eidx[e0 + tid];
    tIdx[tid] = eidx[N_EDGES + e0 + tid];
  }
  {
    const int r = tid & 15, c = tid >> 4;
    #pragma unroll
    for (int rg = 0; rg < 2; ++rg)
      stage_row(ea + (size_t)(e0 + rg*16 + r)*128 + c*8,
                &AFh[rg*2048 + (c*16 + r)*8], &AFl[rg*2048 + (c*16 + r)*8]);
  }
  __syncthreads();

  const int wv = tid >> 6;
  const int mi = (tid & 63) & 15;
  const int kg = (tid & 63) >> 4;

  // ---- phase 1: Ew, Eb via split MFMA
  f32x4 aw[2][2], ab[2][2];
  #pragma unroll
  for (int rg = 0; rg < 2; ++rg)
    #pragma unroll
    for (int t = 0; t < 2; ++t){ aw[rg][t] = (f32x4){0,0,0,0}; ab[rg][t] = (f32x4){0,0,0,0}; }

  #pragma unroll
  for (int ks = 0; ks < 4; ++ks){
    const int ao = ((ks*4 + kg)*16 + mi)*8;
    const int kb = ks*32 + kg*8;
    short8 eh[2], el_[2];
    #pragma unroll
    for (int rg = 0; rg < 2; ++rg){
      eh[rg]  = *reinterpret_cast<const short8*>(&AFh[rg*2048 + ao]);
      el_[rg] = *reinterpret_cast<const short8*>(&AFl[rg*2048 + ao]);
    }
    #pragma unroll
    for (int t = 0; t < 2; ++t){
      const int n = (wv*2 + t)*16 + mi;
      const short8 wh = *reinterpret_cast<const short8*>(&wsw[OFF_WEW + n*128 + kb]);
      const short8 wl = *reinterpret_cast<const short8*>(&wsw[OFF_WEW + WT_SZ + n*128 + kb]);
      const short8 bh = *reinterpret_cast<const short8*>(&wsw[OFF_WEB + n*128 + kb]);
      const short8 bl = *reinterpret_cast<const short8*>(&wsw[OFF_WEB + WT_SZ + n*128 + kb]);
      #pragma unroll
      for (int rg = 0; rg < 2; ++rg){
        aw[rg][t] = __builtin_amdgcn_mfma_f32_16x16x32_bf16(eh[rg], wh, aw[rg][t], 0,0,0);
        ab[rg][t] = __builtin_amdgcn_mfma_f32_16x16x32_bf16(eh[rg], bh, ab[rg][t], 0,0,0);
        aw[rg][t] = __builtin_amdgcn_mfma_f32_16x16x32_bf16(el_[rg], wh, aw[rg][t], 0,0,0);
        ab[rg][t] = __builtin_amdgcn_mfma_f32_16x16x32_bf16(el_[rg], bh, ab[rg][t], 0,0,0);
        aw[rg][t] = __builtin_amdgcn_mfma_f32_16x16x32_bf16(eh[rg], wl, aw[rg][t], 0,0,0);
        ab[rg][t] = __builtin_amdgcn_mfma_f32_16x16x32_bf16(eh[rg], bl, ab[rg][t], 0,0,0);
      }
    }
  }
  __syncthreads();   // ea-frags dead; smem freed for qk

  // ---- qk gather (f32, into the same smem bytes)
  {
    const int r = tid >> 3, cg = tid & 7;
    const float* qp = Qn + (size_t)sIdx[r]*128 + cg*16;
    const float* kp = Kn + (size_t)tIdx[r]*128 + cg*16;
    #pragma unroll
    for (int p = 0; p < 4; ++p){
      const float4 qv = *reinterpret_cast<const float4*>(qp + p*4);
      const float4 kv = *reinterpret_cast<const float4*>(kp + p*4);
      float4 s; s.x = qv.x+kv.x; s.y = qv.y+kv.y; s.z = qv.z+kv.z; s.w = qv.w+kv.w;
      *reinterpret_cast<float4*>(&qkf[r*128 + cg*16 + p*4]) = s;
    }
  }
  __syncthreads();

  // ---- epilogue: af in registers (proven math)
  short afh[2][2][4], afl[2][2][4];
  #pragma unroll
  for (int rg = 0; rg < 2; ++rg)
    #pragma unroll
    for (int t = 0; t < 2; ++t){
      const int n = (wv*2 + t)*16 + mi;
      const float bw = b_Ew[n], bb = b_Eb[n];
      #pragma unroll
      for (int q = 0; q < 4; ++q){
        const float qkv = qkf[(rg*16 + kg*4 + q)*128 + n];
        const float ew  = aw[rg][t][q] + bw;
        const float eb  = ab[rg][t][q] + bb;
        const float pre = qkv * ew;
        const float ssv = pre > 0.f ?  sqrtf( pre + 1e-8f)
                        : (pre < 0.f ? -sqrtf(-pre + 1e-8f) : 0.f);
        const float af = fmaxf(ssv + eb, 0.f);
        short hh, ll; split(af, hh, ll);
        afh[rg][t][q] = hh; afl[rg][t][q] = ll;
      }
    }
  __syncthreads();   // all qk reads done; smem freed for af-frags

  // ---- scatter af (proven address math)
  #pragma unroll
  for (int rg = 0; rg < 2; ++rg)
    #pragma unroll
    for (int t = 0; t < 2; ++t){
      const int c  = (wv*2 + t)*2 + (mi >> 3);
      const int k7 = mi & 7;
      #pragma unroll
      for (int q = 0; q < 4; ++q){
        const int idx = (c*16 + kg*4 + q)*8 + k7;
        AFh[rg*2048 + idx] = afh[rg][t][q];
        AFl[rg*2048 + idx] = afl[rg][t][q];
      }
    }
  __syncthreads();

  // ---- scores = af @ W_A (waves 0,1) + segmax
  if (do_score && wv < 2){
    const int rg = wv;
    f32x4 acc = {0,0,0,0};
    #pragma unroll
    for (int ks = 0; ks < 4; ++ks){
      const int kb = ks*32 + kg*8;
      const int ao = ((ks*4 + kg)*16 + mi)*8;
      const short8 ah = *reinterpret_cast<const short8*>(&AFh[rg*2048 + ao]);
      const short8 al = *reinterpret_cast<const short8*>(&AFl[rg*2048 + ao]);
      const short8 bh = *reinterpret_cast<const short8*>(&wsw[OFF_WA + mi*128 + kb]);
      const short8 bl = *reinterpret_cast<const short8*>(&wsw[OFF_WA + 2048 + mi*128 + kb]);
      acc = __builtin_amdgcn_mfma_f32_16x16x32_bf16(ah, bh, acc, 0,0,0);
      acc = __builtin_amdgcn_mfma_f32_16x16x32_bf16(al, bh, acc, 0,0,0);
      acc = __builtin_amdgcn_mfma_f32_16x16x32_bf16(ah, bl, acc, 0,0,0);
    }
    if (mi < 8){
      const float ba = b_A[mi];
      #pragma unroll
      for (int q = 0; q < 4; ++q){
        const int er = rg*16 + kg*4 + q;
        const float s = san(acc[q] + ba);
        scores[(size_t)(e0 + er)*8 + mi] = s;
        atomicMax(&segmax[(size_t)tIdx[er]*8 + mi], fmap(s));
      }
    }
  }

  // ---- fused Eo = af @ W_Eo (all edges)
  #pragma unroll
  for (int rg = 0; rg < 2; ++rg)
    #pragma unroll
    for (int t2 = 0; t2 < 2; ++t2){
      const int n = (wv*2 + t2)*16 + mi;
      f32x4 acc = {0,0,0,0};
      #pragma unroll
      for (int ks = 0; ks < 4; ++ks){
        const int kb = ks*32 + kg*8;
        const int ao = ((ks*4 + kg)*16 + mi)*8;
        const short8 ah = *reinterpret_cast<const short8*>(&AFh[rg*2048 + ao]);
        const short8 al = *reinterpret_cast<const short8*>(&AFl[rg*2048 + ao]);
        const short8 bh = *reinterpret_cast<const short8*>(&wsw[OFF_WEO + n*128 + kb]);
        const short8 bl = *reinterpret_cast<const short8*>(&wsw[OFF_WEO + WT_SZ + n*128 + kb]);
        acc = __builtin_amdgcn_mfma_f32_16x16x32_bf16(ah, bh, acc, 0,0,0);
        acc = __builtin_amdgcn_mfma_f32_16x16x32_bf16(al, bh, acc, 0,0,0);
        acc = __builtin_amdgcn_mfma_f32_16x16x32_bf16(ah, bl, acc, 0,0,0);
      }
      const float be = b_Eo[n];
      #pragma unroll
      for (int q = 0; q < 4; ++q)
        oute[(size_t)(e0 + rg*16 + kg*4 + q)*128 + n] = san(acc[q] + be);
    }
}

__global__ __launch_bounds__(256) void seg_sum_v18(const float* __restrict__ scores,
    const int* __restrict__ eidx, const unsigned* __restrict__ segmax,
    float* __restrict__ segsum)
{
  int i = blockIdx.x*256 + threadIdx.x;
  if (i >= N_EDGES*8) return;
  int e = i >> 3, h = i & 7;
  int t = eidx[N_EDGES + e];
  float m = funmap(segmax[(size_t)t*8 + h]);
  atomicAdd(&segsum[(size_t)t*8 + h], expf(scores[i] - m));
}

// ---- messages MFMA v18 (tier 2): unnormalized accumulate + den fold (den in WS!)
__global__ __launch_bounds__(256) void messages_mfma_v18(
    const float* __restrict__ ea, const int* __restrict__ eidx,
    const float* __restrict__ Vn, const float* __restrict__ b_Ev,
    const short* __restrict__ wsw,
    const float* __restrict__ scores, const unsigned* __restrict__ segmax,
    float* __restrict__ den, float* __restrict__ agg)
{
  __shared__ __align__(16) short Eh[2][2048], El[2][2048];
  __shared__ int sIdx[32], tIdx[32];

  const int tid = threadIdx.x;
  const int e0  = blockIdx.x * 32;

  if (tid < 32){
    sIdx[tid] = eidx[e0 + tid];
    tIdx[tid] = eidx[N_EDGES + e0 + tid];
  }
  {
    const int r = tid & 15, c = tid >> 4;
    #pragma unroll
    for (int rg = 0; rg < 2; ++rg)
      stage_row(ea + (size_t)(e0 + rg*16 + r)*128 + c*8,
                &Eh[rg][(c*16 + r)*8], &El[rg][(c*16 + r)*8]);
  }
  __syncthreads();

  const int wv = tid >> 6;
  const int mi = (tid & 63) & 15;
  const int kg = (tid & 63) >> 4;

  f32x4 aev[2][2];
  #pragma unroll
  for (int rg = 0; rg < 2; ++rg)
    #pragma unroll
    for (int t = 0; t < 2; ++t) aev[rg][t] = (f32x4){0,0,0,0};

  #pragma unroll
  for (int ks = 0; ks < 4; ++ks){
    const int ao = ((ks*4 + kg)*16 + mi)*8;
    const int kb = ks*32 + kg*8;
    short8 eh[2], el_[2];
    #pragma unroll
    for (int rg = 0; rg < 2; ++rg){
      eh[rg]  = *reinterpret_cast<const short8*>(&Eh[rg][ao]);
      el_[rg] = *reinterpret_cast<const short8*>(&El[rg][ao]);
    }
    #pragma unroll
    for (int t = 0; t < 2; ++t){
      const int n = (wv*2 + t)*16 + mi;
      const short8 bh = *reinterpret_cast<const short8*>(&wsw[OFF_WEV + n*128 + kb]);
      const short8 bl = *reinterpret_cast<const short8*>(&wsw[OFF_WEV + WT_SZ + n*128 + kb]);
      #pragma unroll
      for (int rg = 0; rg < 2; ++rg){
        aev[rg][t] = __builtin_amdgcn_mfma_f32_16x16x32_bf16(eh[rg], bh, aev[rg][t], 0,0,0);
        aev[rg][t] = __builtin_amdgcn_mfma_f32_16x16x32_bf16(el_[rg], bh, aev[rg][t], 0,0,0);
        aev[rg][t] = __builtin_amdgcn_mfma_f32_16x16x32_bf16(eh[rg], bl, aev[rg][t], 0,0,0);
      }
    }
  }

  #pragma unroll
  for (int rg = 0; rg < 2; ++rg)
    #pragma unroll
    for (int t = 0; t < 2; ++t){
      const int n = (wv*2 + t)*16 + mi;
      const int h = n >> 4;
      const float be = b_Ev[n];
      #pragma unroll
      for (int q = 0; q < 4; ++q){
        const int row = rg*16 + kg*4 + q;
        const size_t e = (size_t)e0 + row;
        const int s = sIdx[row], tg = tIdx[row];
        const float m    = funmap(segmax[(size_t)tg*8 + h]);
        const float expw = expf(scores[e*8 + h] - m);
        const float msg  = san((Vn[(size_t)s*128 + n] + aev[rg][t][q] + be) * expw);
        atomicAdd(&agg[(size_t)tg*128 + n], msg);
        if (mi == 0) atomicAdd(&den[(size_t)tg*8 + h], expw);
      }
    }
}

// ---- messages GEMV (tiers 0/1, r12-proven)
__global__ __launch_bounds__(256) void messages_v14f(
    const float* __restrict__ x, const float* __restrict__ ea,
    const int* __restrict__ eidx,
    const float* __restrict__ W_V,  const float* __restrict__ b_V,
    const float* __restrict__ W_Ev, const float* __restrict__ b_Ev,
    const float* __restrict__ scores, const unsigned* __restrict__ segmax,
    const float* __restrict__ segsum, float* __restrict__ agg)
{
  __shared__ float eaT[128][16], xsT[128][16];
  __shared__ int sIdx[16], tIdx[16];

  const int tid = threadIdx.x;
  const int e0  = blockIdx.x * 16;

  if (tid < 16){
    sIdx[tid] = eidx[e0 + tid];
    tIdx[tid] = eidx[N_EDGES + e0 + tid];
  }
  __syncthreads();

  for (int idx = tid; idx < 16*128; idx += 256){
    int r = idx >> 7, k = idx & 127;
    eaT[k][r] = ea[(size_t)(e0 + r)*128 + k];
    xsT[k][r] = x[(size_t)sIdx[r]*128 + k];
  }
  __syncthreads();

  const int j  = tid & 127;
  const int h8 = (tid >> 7) * 8;

  float av[8], ae[8];
  #pragma unroll
  for (int i=0;i<8;i++){ av[i]=0.f; ae[i]=0.f; }

  for (int k=0;k<128;k++){
    const float wv = W_V[(size_t)k*128 + j];
    const float we = W_Ev[(size_t)k*128 + j];
    const float4 s0 = *reinterpret_cast<const float4*>(&xsT[k][h8]);
    const float4 s1 = *reinterpret_cast<const float4*>(&xsT[k][h8+4]);
    const float4 e0v = *reinterpret_cast<const float4*>(&eaT[k][h8]);
    const float4 e1v = *reinterpret_cast<const float4*>(&eaT[k][h8+4]);
    const float sv[8] = {s0.x,s0.y,s0.z,s0.w,s1.x,s1.y,s1.z,s1.w};
    const float ev[8] = {e0v.x,e0v.y,e0v.z,e0v.w,e1v.x,e1v.y,e1v.z,e1v.w};
    #pragma unroll
    for (int i=0;i<8;i++){
      av[i] = fmaf(sv[i], wv, av[i]);
      ae[i] = fmaf(ev[i], we, ae[i]);
    }
  }

  const float bv = b_V[j], be = b_Ev[j];
  const int h = j >> 4;
  #pragma unroll
  for (int i=0;i<8;i++){
    const int el = h8 + i;
    const size_t e = (size_t)e0 + el;
    const int t = tIdx[el];
    const float m   = funmap(segmax[(size_t)t*8 + h]);
    const float d   = segsum[(size_t)t*8 + h] + 1e-16f;
    const float a   = expf(scores[e*8 + h] - m) / d;
    const float msg = san(((av[i] + bv) + (ae[i] + be)) * a);
    atomicAdd(&agg[(size_t)t*128 + j], msg);
  }
}

// ---- x_out = (agg [/ den]) @ W_O + b_O
__global__ __launch_bounds__(256) void oproj_v18(const float* __restrict__ agg,
    const float* __restrict__ den,
    const float* __restrict__ W, const float* __restrict__ bias,
    float* __restrict__ outx)
{
  __shared__ float AT[128][32];
  const int tid  = threadIdx.x;
  const int base = blockIdx.x * 32;

  for (int idx = tid; idx < 32*128; idx += 256){
    int r = idx >> 7, k = idx & 127;
    float v = agg[(size_t)(base + r)*128 + k];
    if (den) v /= (den[(size_t)(base + r)*8 + (k >> 4)] + 1e-16f);
    AT[k][r] = v;
  }
  __syncthreads();

  const int j  = tid & 127;
  const int rb = (tid >> 7) * 16;
  float acc[16];
  #pragma unroll
  for (int i=0;i<16;i++) acc[i] = 0.f;

  for (int k=0;k<128;k++){
    const float w = W[(size_t)k*128 + j];
    const float4 a0 = *reinterpret_cast<const float4*>(&AT[k][rb]);
    const float4 a1 = *reinterpret_cast<const float4*>(&AT[k][rb+4]);
    const float4 a2 = *reinterpret_cast<const float4*>(&AT[k][rb+8]);
    const float4 a3 = *reinterpret_cast<const float4*>(&AT[k][rb+12]);
    const float avv[16] = {a0.x,a0.y,a0.z,a0.w,a1.x,a1.y,a1.z,a1.w,
                           a2.x,a2.y,a2.z,a2.w,a3.x,a3.y,a3.z,a3.w};
    #pragma unroll
    for (int i=0;i<16;i++) acc[i] = fmaf(avv[i], w, acc[i]);
  }

  const float bj = bias[j];
  #pragma unroll
  for (int i=0;i<16;i++)
    outx[(size_t)(base + rb + i)*128 + j] = san(acc[i] + bj);
}

// ---- tier-0 fallback front (r14-proven)
template<bool PREPPED>
__global__ __launch_bounds__(256) void front_v14f(
    const float* __restrict__ x, const float* __restrict__ ea,
    const int* __restrict__ eidx,
    const float* __restrict__ W_Q, const float* __restrict__ b_Q,
    const float* __restrict__ W_K, const float* __restrict__ b_K,
    const float* __restrict__ W_Ew, const float* __restrict__ b_Ew,
    const float* __restrict__ W_Eb, const float* __restrict__ b_Eb,
    const float* __restrict__ b_A,
    const float* __restrict__ W_Eo, const float* __restrict__ b_Eo,
    const short* __restrict__ wsw,
    float* __restrict__ scores, unsigned* __restrict__ segmax,
    float* __restrict__ oute, int eo_min)
{
  __shared__ __align__(16) short AFh[3][2048];
  __shared__ __align__(16) short AFl[3][2048];
  __shared__ int sIdx[16], tIdx[16];

  const int tid = threadIdx.x;
  const int e0  = blockIdx.x * 16;

  if (tid < 16){
    sIdx[tid] = eidx[e0 + tid];
    tIdx[tid] = eidx[N_EDGES + e0 + tid];
  }
  __syncthreads();

  {
    const int r = tid & 15, c = tid >> 4;
    const int off = (c*16 + r)*8;
    stage_row(x  + (size_t)sIdx[r]*128 + c*8, &AFh[0][off], &AFl[0][off]);
    stage_row(x  + (size_t)tIdx[r]*128 + c*8, &AFh[1][off], &AFl[1][off]);
    stage_row(ea + (size_t)(e0 + r)*128 + c*8, &AFh[2][off], &AFl[2][off]);
  }
  __syncthreads();

  const int wv = tid >> 6;
  const int mi = (tid & 63) & 15;
  const int kg = (tid & 63) >> 4;

  f32x4 aq[2], ak[2], aw[2], ab[2];
  #pragma unroll
  for (int t = 0; t < 2; ++t){
    aq[t] = (f32x4){0,0,0,0}; ak[t] = (f32x4){0,0,0,0};
    aw[t] = (f32x4){0,0,0,0}; ab[t] = (f32x4){0,0,0,0};
  }

  #pragma unroll
  for (int ks = 0; ks < 4; ++ks){
    const int ao = ((ks*4 + kg)*16 + mi)*8;
    const short8 xh = *reinterpret_cast<const short8*>(&AFh[0][ao]);
    const short8 xl = *reinterpret_cast<const short8*>(&AFl[0][ao]);
    const short8 th = *reinterpret_cast<const short8*>(&AFh[1][ao]);
    const short8 tl = *reinterpret_cast<const short8*>(&AFl[1][ao]);
    const short8 eh = *reinterpret_cast<const short8*>(&AFh[2][ao]);
    const short8 el = *reinterpret_cast<const short8*>(&AFl[2][ao]);
    const int kb = ks*32 + kg*8;

    #pragma unroll
    for (int t = 0; t < 2; ++t){
      const int n = (wv*2 + t)*16 + mi;
      short8 qh, ql, kh, kl, wh, wl, bh, bl;
      if (PREPPED){
        qh = *reinterpret_cast<const short8*>(&wsw[OFF_WQ  + n*128 + kb]);
        ql = *reinterpret_cast<const short8*>(&wsw[OFF_WQ  + WT_SZ + n*128 + kb]);
        kh = *reinterpret_cast<const short8*>(&wsw[OFF_WK  + n*128 + kb]);
        kl = *reinterpret_cast<const short8*>(&wsw[OFF_WK  + WT_SZ + n*128 + kb]);
        wh = *reinterpret_cast<const short8*>(&wsw[OFF_WEW + n*128 + kb]);
        wl = *reinterpret_cast<const short8*>(&wsw[OFF_WEW + WT_SZ + n*128 + kb]);
        bh = *reinterpret_cast<const short8*>(&wsw[OFF_WEB + n*128 + kb]);
        bl = *reinterpret_cast<const short8*>(&wsw[OFF_WEB + WT_SZ + n*128 + kb]);
      } else {
        #pragma unroll
        for (int q = 0; q < 8; ++q){
          short h, l;
          split(W_Q [(size_t)(kb + q)*128 + n], h, l); qh[q] = h; ql[q] = l;
          split(W_K [(size_t)(kb + q)*128 + n], h, l); kh[q] = h; kl[q] = l;
          split(W_Ew[(size_t)(kb + q)*128 + n], h, l); wh[q] = h; wl[q] = l;
          split(W_Eb[(size_t)(kb + q)*128 + n], h, l); bh[q] = h; bl[q] = l;
        }
      }
      aq[t] = __builtin_amdgcn_mfma_f32_16x16x32_bf16(xh, qh, aq[t], 0,0,0);
      ak[t] = __builtin_amdgcn_mfma_f32_16x16x32_bf16(th, kh, ak[t], 0,0,0);
      aw[t] = __builtin_amdgcn_mfma_f32_16x16x32_bf16(eh, wh, aw[t], 0,0,0);
      ab[t] = __builtin_amdgcn_mfma_f32_16x16x32_bf16(eh, bh, ab[t], 0,0,0);
      aq[t] = __builtin_amdgcn_mfma_f32_16x16x32_bf16(xl, qh, aq[t], 0,0,0);
      ak[t] = __builtin_amdgcn_mfma_f32_16x16x32_bf16(tl, kh, ak[t], 0,0,0);
      aw[t] = __builtin_amdgcn_mfma_f32_16x16x32_bf16(el, wh, aw[t], 0,0,0);
      ab[t] = __builtin_amdgcn_mfma_f32_16x16x32_bf16(el, bh, ab[t], 0,0,0);
      aq[t] = __builtin_amdgcn_mfma_f32_16x16x32_bf16(xh, ql, aq[t], 0,0,0);
      ak[t] = __builtin_amdgcn_mfma_f32_16x16x32_bf16(th, kl, ak[t], 0,0,0);
      aw[t] = __builtin_amdgcn_mfma_f32_16x16x32_bf16(eh, wl, aw[t], 0,0,0);
      ab[t] = __builtin_amdgcn_mfma_f32_16x16x32_bf16(eh, bl, ab[t], 0,0,0);
    }
  }

  short afh[2][4], afl[2][4];
  #pragma unroll
  for (int t = 0; t < 2; ++t){
    const int n = (wv*2 + t)*16 + mi;
    const float bqk = b_Q[n] + b_K[n];
    const float bw  = b_Ew[n];
    const float bb  = b_Eb[n];
    #pragma unroll
    for (int q = 0; q < 4; ++q){
      const float qk = aq[t][q] + ak[t][q] + bqk;
      const float ew = aw[t][q] + bw;
      const float eb = ab[t][q] + bb;
      const float pre = qk * ew;
      const float ssv = pre > 0.f ?  sqrtf( pre + 1e-8f)
                      : (pre < 0.f ? -sqrtf(-pre + 1e-8f) : 0.f);
      const float af = fmaxf(ssv + eb, 0.f);
      short hh, ll; split(af, hh, ll);
      afh[t][q] = hh; afl[t][q] = ll;
    }
  }
  __syncthreads();

  #pragma unroll
  for (int t = 0; t < 2; ++t){
    const int c  = (wv*2 + t)*2 + (mi >> 3);
    const int k7 = mi & 7;
    #pragma unroll
    for (int q = 0; q < 4; ++q){
      const int idx = (c*16 + kg*4 + q)*8 + k7;
      AFh[0][idx] = afh[t][q];
      AFl[0][idx] = afl[t][q];
    }
  }
  __syncthreads();

  if (PREPPED && wv == 0){
    f32x4 acc = {0,0,0,0};
    #pragma unroll
    for (int ks = 0; ks < 4; ++ks){
      const int kb = ks*32 + kg*8;
      const int ao = ((ks*4 + kg)*16 + mi)*8;
      const short8 ah = *reinterpret_cast<const short8*>(&AFh[0][ao]);
      const short8 al = *reinterpret_cast<const short8*>(&AFl[0][ao]);
      const short8 bh = *reinterpret_cast<const short8*>(&wsw[OFF_WA + mi*128 + kb]);
      const short8 bl = *reinterpret_cast<const short8*>(&wsw[OFF_WA + 2048 + mi*128 + kb]);
      acc = __builtin_amdgcn_mfma_f32_16x16x32_bf16(ah, bh, acc, 0,0,0);
      acc = __builtin_amdgcn_mfma_f32_16x16x32_bf16(al, bh, acc, 0,0,0);
      acc = __builtin_amdgcn_mfma_f32_16x16x32_bf16(ah, bl, acc, 0,0,0);
    }
    if (mi < 8){
      const float ba = b_A[mi];
      #pragma unroll
      for (int q = 0; q < 4; ++q){
        const int er = kg*4 + q;
        const float s = san(acc[q] + ba);
        scores[(size_t)(e0 + er)*8 + mi] = s;
        atomicMax(&segmax[(size_t)tIdx[er]*8 + mi], fmap(s));
      }
    }
  }

  if (e0 >= eo_min){
    #pragma unroll
    for (int t2 = 0; t2 < 2; ++t2){
      const int n = (wv*2 + t2)*16 + mi;
      f32x4 acc = {0,0,0,0};
      #pragma unroll
      for (int ks = 0; ks < 4; ++ks){
        const int kb = ks*32 + kg*8;
        const int ao = ((ks*4 + kg)*16 + mi)*8;
        const short8 ah = *reinterpret_cast<const short8*>(&AFh[0][ao]);
        const short8 al = *reinterpret_cast<const short8*>(&AFl[0][ao]);
        short8 bh, bl;
        if (PREPPED){
          bh = *reinterpret_cast<const short8*>(&wsw[OFF_WEO + n*128 + kb]);
          bl = *reinterpret_cast<const short8*>(&wsw[OFF_WEO + WT_SZ + n*128 + kb]);
        } else {
          #pragma unroll
          for (int q = 0; q < 8; ++q){
            short h, l; split(W_Eo[(size_t)(kb + q)*128 + n], h, l); bh[q] = h; bl[q] = l;
          }
        }
        acc = __builtin_amdgcn_mfma_f32_16x16x32_bf16(ah, bh, acc, 0,0,0);
        acc = __builtin_amdgcn_mfma_f32_16x16x32_bf16(al, bh, acc, 0,0,0);
        acc = __builtin_amdgcn_mfma_f32_16x16x32_bf16(ah, bl, acc, 0,0,0);
      }
      const float be = b_Eo[n];
      #pragma unroll
      for (int q = 0; q < 4; ++q)
        oute[(size_t)(e0 + kg*4 + q)*128 + n] = san(acc[q] + be);
    }
  }
}

extern "C" void kernel_launch(void* const* d_in, const int* in_sizes, int n_in,
                              void* d_out, int out_size, void* d_ws, size_t ws_size,
                              hipStream_t stream)
{
  (void)in_sizes; (void)n_in; (void)out_size;
  const float* x    = (const float*)d_in[0];
  const float* ea   = (const float*)d_in[1];
  const int*   eidx = (const int*)d_in[2];
  const float* W_Q  = (const float*)d_in[4];  const float* b_Q  = (const float*)d_in[5];
  const float* W_K  = (const float*)d_in[6];  const float* b_K  = (const float*)d_in[7];
  const float* W_V  = (const float*)d_in[8];  const float* b_V  = (const float*)d_in[9];
  const float* W_Ew = (const float*)d_in[10]; const float* b_Ew = (const float*)d_in[11];
  const float* W_Eb = (const float*)d_in[12]; const float* b_Eb = (const float*)d_in[13];
  const float* W_Ev = (const float*)d_in[14]; const float* b_Ev = (const float*)d_in[15];
  const float* W_O  = (const float*)d_in[16]; const float* b_O  = (const float*)d_in[17];
  const float* W_Eo = (const float*)d_in[18]; const float* b_Eo = (const float*)d_in[19];
  const float* W_A  = (const float*)d_in[20]; const float* b_A  = (const float*)d_in[21];

  float* out_x = (float*)d_out;
  float* oute  = out_x + OUT_E_ELEM;

  float*    scores = (float*)d_out;
  unsigned* segmax = (unsigned*)((char*)d_out + SCORES_B);
  float*    segsum = (float*)((char*)d_out + SCORES_B + SEG_B);   // tiers 0/1 only

  const size_t SZ_NODEF = (size_t)N_NODES*128*4;       // 51.2 MB
  const size_t NEED_QK   = 2*SZ_NODEF + WSW_BYTES;     // ~102.9 MB
  const size_t NEED_FULL = 3*SZ_NODEF + WSW_BYTES;     // ~154.1 MB

  const int tier = (ws_size >= NEED_FULL) ? 2 : (ws_size >= NEED_QK) ? 1 : 0;

  dim3 blk(256);
  hipMemsetAsync((void*)segmax, 0, 2*SEG_B, stream);

  if (tier >= 1){
    char*  ws  = (char*)d_ws;
    float* Qn  = (float*)ws;
    float* Kn  = (float*)(ws + SZ_NODEF);
    float* Vn  = (tier == 2) ? (float*)(ws + 2*SZ_NODEF) : nullptr;
    short* wsw = (short*)(ws + ((tier == 2) ? 3 : 2)*SZ_NODEF);
    float* agg = Qn;    // Qn dead after front
    float* den = Kn;    // Kn dead after front (tier-2 den lives in WS, not d_out!)

    prep_v18<<<dim3(912), dim3(128), 0, stream>>>(W_Q, W_K, W_Ew, W_Eb, W_Eo, W_V, W_Ev, W_A, wsw);

    nodeproj_v18<<<dim3(N_NODES/32), blk, 0, stream>>>(x, wsw, b_Q, b_K, b_V,
        Qn, Kn, Vn, tier == 2 ? 1 : 0);

    front_qk_v18<<<dim3(N_EDGES/32), blk, 0, stream>>>(ea, eidx, Qn, Kn,
        b_Ew, b_Eb, b_A, b_Eo, wsw, scores, segmax, oute, 1);

    // Qn(=agg) and Kn(=den) are adjacent: one memset covers both
    hipMemsetAsync((void*)agg, 0, AGG_BYTES + SEG_B, stream);

    if (tier == 2){
      messages_mfma_v18<<<dim3(N_EDGES/32), blk, 0, stream>>>(ea, eidx, Vn, b_Ev,
          wsw, scores, segmax, den, agg);
      oproj_v18<<<dim3(N_NODES/32), blk, 0, stream>>>(agg, den, W_O, b_O, out_x);
    } else {
      seg_sum_v18<<<dim3((N_EDGES*8 + 255)/256), blk, 0, stream>>>(scores, eidx, segmax, segsum);
      messages_v14f<<<dim3(N_EDGES/16), blk, 0, stream>>>(x, ea, eidx,
          W_V, b_V, W_Ev, b_Ev, scores, segmax, segsum, agg);
      oproj_v18<<<dim3(N_NODES/32), blk, 0, stream>>>(agg, nullptr, W_O, b_O, out_x);
    }

  } else {
    // ---- tier 0 fallback: r14-proven pipeline; wsw + agg inside d_out ----
    short* wsw = (short*)((char*)d_out + WSW_OFF);
    float* agg = oute;                             // rows [0, EO_MIN)

    hipMemsetAsync((void*)agg, 0, AGG_BYTES, stream);

    prep_v18<<<dim3(912), dim3(128), 0, stream>>>(W_Q, W_K, W_Ew, W_Eb, W_Eo, W_V, W_Ev, W_A, wsw);

    front_v14f<true><<<dim3(N_EDGES/16), blk, 0, stream>>>(x, ea, eidx,
        W_Q, b_Q, W_K, b_K, W_Ew, b_Ew, W_Eb, b_Eb, b_A, W_Eo, b_Eo, wsw,
        scores, segmax, oute, EO_MIN);

    seg_sum_v18<<<dim3((N_EDGES*8 + 255)/256), blk, 0, stream>>>(scores, eidx, segmax, segsum);

    messages_v14f<<<dim3(N_EDGES/16), blk, 0, stream>>>(x, ea, eidx,
        W_V, b_V, W_Ev, b_Ev, scores, segmax, segsum, agg);

    oproj_v18<<<dim3(N_NODES/32), blk, 0, stream>>>(agg, nullptr, W_O, b_O, out_x);

    front_v14f<false><<<dim3(EO_MIN/16), blk, 0, stream>>>(x, ea, eidx,
        W_Q, b_Q, W_K, b_K, W_Ew, b_Ew, W_Eb, b_Eb, b_A, W_Eo, b_Eo, nullptr,
        nullptr, nullptr, oute, 0);
  }
}

// Round 19
// 1000.593 us; speedup vs baseline: 1.0366x; 1.0366x over previous
//
#include <hip/hip_runtime.h>
#include <hip/hip_bf16.h>

typedef __hip_bfloat16 bf16;

#define N_NODES 100000
#define N_EDGES 400000
#define EO_MIN  100000   // tier-0 fallback only

// ---- f32 geometry of d_out (proven r12-r16) ----
#define OUT_E_ELEM ((size_t)N_NODES*128)
#define SCORES_B   ((size_t)N_EDGES*8*4)            // 12.8 MB
#define SEG_B      ((size_t)N_NODES*8*4)            //  3.2 MB
#define AGG_BYTES  ((size_t)N_NODES*128*4)          // 51.2 MB
#define WSW_OFF    (SCORES_B + 2*SEG_B)             // fallback wsw inside d_out

// prepped-weight tables (shorts): WT[n][k] transposed, hi then lo.
#define WT_SZ   16384
#define OFF_WQ  (0*WT_SZ)
#define OFF_WK  (2*WT_SZ)
#define OFF_WEW (4*WT_SZ)
#define OFF_WEB (6*WT_SZ)
#define OFF_WEO (8*WT_SZ)
#define OFF_WV  (10*WT_SZ)
#define OFF_WEV (12*WT_SZ)
#define OFF_WA  (14*WT_SZ)    // 16x128 padded, hi + lo(+2048)
#define WSW_SHORTS (14*WT_SZ + 2*2048)
#define WSW_BYTES  ((size_t)WSW_SHORTS*2)

using short8 = __attribute__((ext_vector_type(8))) short;
using f32x4  = __attribute__((ext_vector_type(4))) float;

__device__ __forceinline__ float b2f(bf16 v){ return __bfloat162float(v); }
__device__ __forceinline__ bf16  f2b(float v){ return __float2bfloat16(v); }
__device__ __forceinline__ short bits(bf16 v){ short s; __builtin_memcpy(&s, &v, 2); return s; }
__device__ __forceinline__ void split(float v, short& h, short& l){
  bf16 hb = f2b(v);
  h = bits(hb);
  l = bits(f2b(v - b2f(hb)));
}
__device__ __forceinline__ float san(float v){
  return (v == v && fabsf(v) < 1e30f) ? v : 0.f;
}
__device__ __forceinline__ unsigned fmap(float f){
  unsigned u = __float_as_uint(f);
  return (u & 0x80000000u) ? ~u : (u | 0x80000000u);
}
__device__ __forceinline__ float funmap(unsigned u){
  unsigned b = (u & 0x80000000u) ? (u ^ 0x80000000u) : ~u;
  return __uint_as_float(b);
}

// ---- unified weight prep (r16-proven)
__global__ void prep_v19(const float* __restrict__ W_Q, const float* __restrict__ W_K,
                         const float* __restrict__ W_Ew, const float* __restrict__ W_Eb,
                         const float* __restrict__ W_Eo, const float* __restrict__ W_V,
                         const float* __restrict__ W_Ev, const float* __restrict__ W_A,
                         short* __restrict__ wsw)
{
  const int b = blockIdx.x;
  if (b < 896){
    const int mi = b >> 7, n = b & 127;
    const float* W = (mi==0)?W_Q:(mi==1)?W_K:(mi==2)?W_Ew:(mi==3)?W_Eb:(mi==4)?W_Eo:(mi==5)?W_V:W_Ev;
    short* dh = wsw + mi*2*WT_SZ;
    short* dl = dh + WT_SZ;
    for (int k = threadIdx.x; k < 128; k += 128){
      short h, l; split(W[(size_t)k*128 + n], h, l);
      dh[n*128 + k] = h; dl[n*128 + k] = l;
    }
  } else {
    const int n = b - 896;
    short* dh = wsw + OFF_WA;
    short* dl = dh + 2048;
    for (int k = threadIdx.x; k < 128; k += 128){
      float v = (n < 8) ? W_A[(size_t)k*8 + n] : 0.f;
      short h, l; split(v, h, l);
      dh[n*128 + k] = h; dl[n*128 + k] = l;
    }
  }
}

__device__ __forceinline__ void stage_row(const float* __restrict__ src,
                                          short* __restrict__ dh, short* __restrict__ dl){
  const float4 v0 = *reinterpret_cast<const float4*>(src);
  const float4 v1 = *reinterpret_cast<const float4*>(src + 4);
  const float vv[8] = {v0.x, v0.y, v0.z, v0.w, v1.x, v1.y, v1.z, v1.w};
  short8 h, l;
  #pragma unroll
  for (int q = 0; q < 8; ++q){ short hh, ll; split(vv[q], hh, ll); h[q] = hh; l[q] = ll; }
  *reinterpret_cast<short8*>(dh) = h;
  *reinterpret_cast<short8*>(dl) = l;
}

// ---- nodeproj (r15/r16-proven)
__global__ __launch_bounds__(256) void nodeproj_v19(
    const float* __restrict__ x, const short* __restrict__ wsw,
    const float* __restrict__ b_Q, const float* __restrict__ b_K,
    const float* __restrict__ b_V,
    float* __restrict__ Qn, float* __restrict__ Kn, float* __restrict__ Vn,
    int do_v)
{
  __shared__ __align__(16) short Xh[2][2048], Xl[2][2048];
  const int tid = threadIdx.x;
  const int n0  = blockIdx.x * 32;

  {
    const int r = tid & 15, c = tid >> 4;
    #pragma unroll
    for (int rg = 0; rg < 2; ++rg)
      stage_row(x + (size_t)(n0 + rg*16 + r)*128 + c*8,
                &Xh[rg][(c*16 + r)*8], &Xl[rg][(c*16 + r)*8]);
  }
  __syncthreads();

  const int wv = tid >> 6;
  const int mi = (tid & 63) & 15;
  const int kg = (tid & 63) >> 4;

  f32x4 aQ[2][2], aK[2][2], aV[2][2];
  #pragma unroll
  for (int rg = 0; rg < 2; ++rg)
    #pragma unroll
    for (int t = 0; t < 2; ++t){
      aQ[rg][t] = (f32x4){0,0,0,0}; aK[rg][t] = (f32x4){0,0,0,0}; aV[rg][t] = (f32x4){0,0,0,0};
    }

  #pragma unroll
  for (int ks = 0; ks < 4; ++ks){
    const int ao = ((ks*4 + kg)*16 + mi)*8;
    const int kb = ks*32 + kg*8;
    short8 xh[2], xl[2];
    #pragma unroll
    for (int rg = 0; rg < 2; ++rg){
      xh[rg] = *reinterpret_cast<const short8*>(&Xh[rg][ao]);
      xl[rg] = *reinterpret_cast<const short8*>(&Xl[rg][ao]);
    }
    #pragma unroll
    for (int t = 0; t < 2; ++t){
      const int n = (wv*2 + t)*16 + mi;
      const short8 qh = *reinterpret_cast<const short8*>(&wsw[OFF_WQ + n*128 + kb]);
      const short8 ql = *reinterpret_cast<const short8*>(&wsw[OFF_WQ + WT_SZ + n*128 + kb]);
      const short8 kh = *reinterpret_cast<const short8*>(&wsw[OFF_WK + n*128 + kb]);
      const short8 kl = *reinterpret_cast<const short8*>(&wsw[OFF_WK + WT_SZ + n*128 + kb]);
      const short8 vh = *reinterpret_cast<const short8*>(&wsw[OFF_WV + n*128 + kb]);
      const short8 vl = *reinterpret_cast<const short8*>(&wsw[OFF_WV + WT_SZ + n*128 + kb]);
      #pragma unroll
      for (int rg = 0; rg < 2; ++rg){
        aQ[rg][t] = __builtin_amdgcn_mfma_f32_16x16x32_bf16(xh[rg], qh, aQ[rg][t], 0,0,0);
        aK[rg][t] = __builtin_amdgcn_mfma_f32_16x16x32_bf16(xh[rg], kh, aK[rg][t], 0,0,0);
        aQ[rg][t] = __builtin_amdgcn_mfma_f32_16x16x32_bf16(xl[rg], qh, aQ[rg][t], 0,0,0);
        aK[rg][t] = __builtin_amdgcn_mfma_f32_16x16x32_bf16(xl[rg], kh, aK[rg][t], 0,0,0);
        aQ[rg][t] = __builtin_amdgcn_mfma_f32_16x16x32_bf16(xh[rg], ql, aQ[rg][t], 0,0,0);
        aK[rg][t] = __builtin_amdgcn_mfma_f32_16x16x32_bf16(xh[rg], kl, aK[rg][t], 0,0,0);
        if (do_v){
          aV[rg][t] = __builtin_amdgcn_mfma_f32_16x16x32_bf16(xh[rg], vh, aV[rg][t], 0,0,0);
          aV[rg][t] = __builtin_amdgcn_mfma_f32_16x16x32_bf16(xl[rg], vh, aV[rg][t], 0,0,0);
          aV[rg][t] = __builtin_amdgcn_mfma_f32_16x16x32_bf16(xh[rg], vl, aV[rg][t], 0,0,0);
        }
      }
    }
  }

  #pragma unroll
  for (int rg = 0; rg < 2; ++rg)
    #pragma unroll
    for (int t = 0; t < 2; ++t){
      const int n = (wv*2 + t)*16 + mi;
      const float bq = b_Q[n], bk = b_K[n], bv = b_V[n];
      #pragma unroll
      for (int q = 0; q < 4; ++q){
        const size_t row = n0 + rg*16 + kg*4 + q;
        Qn[row*128 + n] = aQ[rg][t][q] + bq;
        Kn[row*128 + n] = aK[rg][t][q] + bk;
        if (do_v) Vn[row*128 + n] = aV[rg][t][q] + bv;
      }
    }
}

// ---- MFMA front v19: v18 LDS-multiplex body + T14 early register gather of
// Qn/Kn (loads issued at kernel entry; combined+written to smem after phase 1).
__global__ __launch_bounds__(256) void front_qk_v19(
    const float* __restrict__ ea, const int* __restrict__ eidx,
    const float* __restrict__ Qn, const float* __restrict__ Kn,
    const float* __restrict__ b_Ew, const float* __restrict__ b_Eb,
    const float* __restrict__ b_A,  const float* __restrict__ b_Eo,
    const short* __restrict__ wsw,
    float* __restrict__ scores, unsigned* __restrict__ segmax,
    float* __restrict__ oute, int do_score)
{
  __shared__ __align__(16) char smem[16384];
  __shared__ int sIdx[32], tIdx[32];
  short* AFh = (short*)smem;            // [2][2048]
  short* AFl = (short*)(smem + 8192);   // [2][2048]
  float* qkf = (float*)smem;            // [32][128] (aliases AFh/AFl)

  const int tid = threadIdx.x;
  const int e0  = blockIdx.x * 32;

  // ---- T14: issue Qn/Kn gather loads IMMEDIATELY (per-thread indices straight
  // from global, no LDS dependency) — they complete under phase-1 MFMA.
  const int gr = tid >> 3, gc = tid & 7;
  const int gse = eidx[e0 + gr];
  const int gte = eidx[N_EDGES + e0 + gr];
  float4 qv[4], kv[4];
  {
    const float* qp = Qn + (size_t)gse*128 + gc*16;
    const float* kp = Kn + (size_t)gte*128 + gc*16;
    #pragma unroll
    for (int p = 0; p < 4; ++p){
      qv[p] = *reinterpret_cast<const float4*>(qp + p*4);
      kv[p] = *reinterpret_cast<const float4*>(kp + p*4);
    }
  }

  if (tid < 32){
    sIdx[tid] = eidx[e0 + tid];
    tIdx[tid] = eidx[N_EDGES + e0 + tid];
  }
  {
    const int r = tid & 15, c = tid >> 4;
    #pragma unroll
    for (int rg = 0; rg < 2; ++rg)
      stage_row(ea + (size_t)(e0 + rg*16 + r)*128 + c*8,
                &AFh[rg*2048 + (c*16 + r)*8], &AFl[rg*2048 + (c*16 + r)*8]);
  }
  __syncthreads();

  const int wv = tid >> 6;
  const int mi = (tid & 63) & 15;
  const int kg = (tid & 63) >> 4;

  // ---- phase 1: Ew, Eb via split MFMA (gather loads in flight)
  f32x4 aw[2][2], ab[2][2];
  #pragma unroll
  for (int rg = 0; rg < 2; ++rg)
    #pragma unroll
    for (int t = 0; t < 2; ++t){ aw[rg][t] = (f32x4){0,0,0,0}; ab[rg][t] = (f32x4){0,0,0,0}; }

  #pragma unroll
  for (int ks = 0; ks < 4; ++ks){
    const int ao = ((ks*4 + kg)*16 + mi)*8;
    const int kb = ks*32 + kg*8;
    short8 eh[2], el_[2];
    #pragma unroll
    for (int rg = 0; rg < 2; ++rg){
      eh[rg]  = *reinterpret_cast<const short8*>(&AFh[rg*2048 + ao]);
      el_[rg] = *reinterpret_cast<const short8*>(&AFl[rg*2048 + ao]);
    }
    #pragma unroll
    for (int t = 0; t < 2; ++t){
      const int n = (wv*2 + t)*16 + mi;
      const short8 wh = *reinterpret_cast<const short8*>(&wsw[OFF_WEW + n*128 + kb]);
      const short8 wl = *reinterpret_cast<const short8*>(&wsw[OFF_WEW + WT_SZ + n*128 + kb]);
      const short8 bh = *reinterpret_cast<const short8*>(&wsw[OFF_WEB + n*128 + kb]);
      const short8 bl = *reinterpret_cast<const short8*>(&wsw[OFF_WEB + WT_SZ + n*128 + kb]);
      #pragma unroll
      for (int rg = 0; rg < 2; ++rg){
        aw[rg][t] = __builtin_amdgcn_mfma_f32_16x16x32_bf16(eh[rg], wh, aw[rg][t], 0,0,0);
        ab[rg][t] = __builtin_amdgcn_mfma_f32_16x16x32_bf16(eh[rg], bh, ab[rg][t], 0,0,0);
        aw[rg][t] = __builtin_amdgcn_mfma_f32_16x16x32_bf16(el_[rg], wh, aw[rg][t], 0,0,0);
        ab[rg][t] = __builtin_amdgcn_mfma_f32_16x16x32_bf16(el_[rg], bh, ab[rg][t], 0,0,0);
        aw[rg][t] = __builtin_amdgcn_mfma_f32_16x16x32_bf16(eh[rg], wl, aw[rg][t], 0,0,0);
        ab[rg][t] = __builtin_amdgcn_mfma_f32_16x16x32_bf16(eh[rg], bl, ab[rg][t], 0,0,0);
      }
    }
  }
  __syncthreads();   // ea-frags dead; smem freed for qk

  // ---- qk write-late (T14): combine registers, store to the freed smem
  {
    #pragma unroll
    for (int p = 0; p < 4; ++p){
      float4 s;
      s.x = qv[p].x + kv[p].x; s.y = qv[p].y + kv[p].y;
      s.z = qv[p].z + kv[p].z; s.w = qv[p].w + kv[p].w;
      *reinterpret_cast<float4*>(&qkf[gr*128 + gc*16 + p*4]) = s;
    }
  }
  __syncthreads();

  // ---- epilogue: af in registers (proven math)
  short afh[2][2][4], afl[2][2][4];
  #pragma unroll
  for (int rg = 0; rg < 2; ++rg)
    #pragma unroll
    for (int t = 0; t < 2; ++t){
      const int n = (wv*2 + t)*16 + mi;
      const float bw = b_Ew[n], bb = b_Eb[n];
      #pragma unroll
      for (int q = 0; q < 4; ++q){
        const float qkv = qkf[(rg*16 + kg*4 + q)*128 + n];
        const float ew  = aw[rg][t][q] + bw;
        const float eb  = ab[rg][t][q] + bb;
        const float pre = qkv * ew;
        const float ssv = pre > 0.f ?  sqrtf( pre + 1e-8f)
                        : (pre < 0.f ? -sqrtf(-pre + 1e-8f) : 0.f);
        const float af = fmaxf(ssv + eb, 0.f);
        short hh, ll; split(af, hh, ll);
        afh[rg][t][q] = hh; afl[rg][t][q] = ll;
      }
    }
  __syncthreads();   // all qk reads done; smem freed for af-frags

  // ---- scatter af (proven address math)
  #pragma unroll
  for (int rg = 0; rg < 2; ++rg)
    #pragma unroll
    for (int t = 0; t < 2; ++t){
      const int c  = (wv*2 + t)*2 + (mi >> 3);
      const int k7 = mi & 7;
      #pragma unroll
      for (int q = 0; q < 4; ++q){
        const int idx = (c*16 + kg*4 + q)*8 + k7;
        AFh[rg*2048 + idx] = afh[rg][t][q];
        AFl[rg*2048 + idx] = afl[rg][t][q];
      }
    }
  __syncthreads();

  // ---- scores = af @ W_A (waves 0,1) + segmax
  if (do_score && wv < 2){
    const int rg = wv;
    f32x4 acc = {0,0,0,0};
    #pragma unroll
    for (int ks = 0; ks < 4; ++ks){
      const int kb = ks*32 + kg*8;
      const int ao = ((ks*4 + kg)*16 + mi)*8;
      const short8 ah = *reinterpret_cast<const short8*>(&AFh[rg*2048 + ao]);
      const short8 al = *reinterpret_cast<const short8*>(&AFl[rg*2048 + ao]);
      const short8 bh = *reinterpret_cast<const short8*>(&wsw[OFF_WA + mi*128 + kb]);
      const short8 bl = *reinterpret_cast<const short8*>(&wsw[OFF_WA + 2048 + mi*128 + kb]);
      acc = __builtin_amdgcn_mfma_f32_16x16x32_bf16(ah, bh, acc, 0,0,0);
      acc = __builtin_amdgcn_mfma_f32_16x16x32_bf16(al, bh, acc, 0,0,0);
      acc = __builtin_amdgcn_mfma_f32_16x16x32_bf16(ah, bl, acc, 0,0,0);
    }
    if (mi < 8){
      const float ba = b_A[mi];
      #pragma unroll
      for (int q = 0; q < 4; ++q){
        const int er = rg*16 + kg*4 + q;
        const float s = san(acc[q] + ba);
        scores[(size_t)(e0 + er)*8 + mi] = s;
        atomicMax(&segmax[(size_t)tIdx[er]*8 + mi], fmap(s));
      }
    }
  }

  // ---- fused Eo = af @ W_Eo (all edges)
  #pragma unroll
  for (int rg = 0; rg < 2; ++rg)
    #pragma unroll
    for (int t2 = 0; t2 < 2; ++t2){
      const int n = (wv*2 + t2)*16 + mi;
      f32x4 acc = {0,0,0,0};
      #pragma unroll
      for (int ks = 0; ks < 4; ++ks){
        const int kb = ks*32 + kg*8;
        const int ao = ((ks*4 + kg)*16 + mi)*8;
        const short8 ah = *reinterpret_cast<const short8*>(&AFh[rg*2048 + ao]);
        const short8 al = *reinterpret_cast<const short8*>(&AFl[rg*2048 + ao]);
        const short8 bh = *reinterpret_cast<const short8*>(&wsw[OFF_WEO + n*128 + kb]);
        const short8 bl = *reinterpret_cast<const short8*>(&wsw[OFF_WEO + WT_SZ + n*128 + kb]);
        acc = __builtin_amdgcn_mfma_f32_16x16x32_bf16(ah, bh, acc, 0,0,0);
        acc = __builtin_amdgcn_mfma_f32_16x16x32_bf16(al, bh, acc, 0,0,0);
        acc = __builtin_amdgcn_mfma_f32_16x16x32_bf16(ah, bl, acc, 0,0,0);
      }
      const float be = b_Eo[n];
      #pragma unroll
      for (int q = 0; q < 4; ++q)
        oute[(size_t)(e0 + rg*16 + kg*4 + q)*128 + n] = san(acc[q] + be);
    }
}

__global__ __launch_bounds__(256) void seg_sum_v19(const float* __restrict__ scores,
    const int* __restrict__ eidx, const unsigned* __restrict__ segmax,
    float* __restrict__ segsum)
{
  int i = blockIdx.x*256 + threadIdx.x;
  if (i >= N_EDGES*8) return;
  int e = i >> 3, h = i & 7;
  int t = eidx[N_EDGES + e];
  float m = funmap(segmax[(size_t)t*8 + h]);
  atomicAdd(&segsum[(size_t)t*8 + h], expf(scores[i] - m));
}

// ---- messages MFMA (r16-proven, normalized): Ev via split MFMA,
// msg = (Vn[src] + Ev + b)*alpha, atomicAdd into agg[tgt].
__global__ __launch_bounds__(256) void messages_mfma_v19(
    const float* __restrict__ ea, const int* __restrict__ eidx,
    const float* __restrict__ Vn, const float* __restrict__ b_Ev,
    const short* __restrict__ wsw,
    const float* __restrict__ scores, const unsigned* __restrict__ segmax,
    const float* __restrict__ segsum, float* __restrict__ agg)
{
  __shared__ __align__(16) short Eh[2][2048], El[2][2048];
  __shared__ int sIdx[32], tIdx[32];

  const int tid = threadIdx.x;
  const int e0  = blockIdx.x * 32;

  if (tid < 32){
    sIdx[tid] = eidx[e0 + tid];
    tIdx[tid] = eidx[N_EDGES + e0 + tid];
  }
  {
    const int r = tid & 15, c = tid >> 4;
    #pragma unroll
    for (int rg = 0; rg < 2; ++rg)
      stage_row(ea + (size_t)(e0 + rg*16 + r)*128 + c*8,
                &Eh[rg][(c*16 + r)*8], &El[rg][(c*16 + r)*8]);
  }
  __syncthreads();

  const int wv = tid >> 6;
  const int mi = (tid & 63) & 15;
  const int kg = (tid & 63) >> 4;

  f32x4 aev[2][2];
  #pragma unroll
  for (int rg = 0; rg < 2; ++rg)
    #pragma unroll
    for (int t = 0; t < 2; ++t) aev[rg][t] = (f32x4){0,0,0,0};

  #pragma unroll
  for (int ks = 0; ks < 4; ++ks){
    const int ao = ((ks*4 + kg)*16 + mi)*8;
    const int kb = ks*32 + kg*8;
    short8 eh[2], el_[2];
    #pragma unroll
    for (int rg = 0; rg < 2; ++rg){
      eh[rg]  = *reinterpret_cast<const short8*>(&Eh[rg][ao]);
      el_[rg] = *reinterpret_cast<const short8*>(&El[rg][ao]);
    }
    #pragma unroll
    for (int t = 0; t < 2; ++t){
      const int n = (wv*2 + t)*16 + mi;
      const short8 bh = *reinterpret_cast<const short8*>(&wsw[OFF_WEV + n*128 + kb]);
      const short8 bl = *reinterpret_cast<const short8*>(&wsw[OFF_WEV + WT_SZ + n*128 + kb]);
      #pragma unroll
      for (int rg = 0; rg < 2; ++rg){
        aev[rg][t] = __builtin_amdgcn_mfma_f32_16x16x32_bf16(eh[rg], bh, aev[rg][t], 0,0,0);
        aev[rg][t] = __builtin_amdgcn_mfma_f32_16x16x32_bf16(el_[rg], bh, aev[rg][t], 0,0,0);
        aev[rg][t] = __builtin_amdgcn_mfma_f32_16x16x32_bf16(eh[rg], bl, aev[rg][t], 0,0,0);
      }
    }
  }

  #pragma unroll
  for (int rg = 0; rg < 2; ++rg)
    #pragma unroll
    for (int t = 0; t < 2; ++t){
      const int n = (wv*2 + t)*16 + mi;
      const int h = n >> 4;
      const float be = b_Ev[n];
      #pragma unroll
      for (int q = 0; q < 4; ++q){
        const int row = rg*16 + kg*4 + q;
        const size_t e = (size_t)e0 + row;
        const int s = sIdx[row], tg = tIdx[row];
        const float m   = funmap(segmax[(size_t)tg*8 + h]);
        const float den = segsum[(size_t)tg*8 + h] + 1e-16f;
        const float a   = expf(scores[e*8 + h] - m) / den;
        const float msg = san((Vn[(size_t)s*128 + n] + aev[rg][t][q] + be) * a);
        atomicAdd(&agg[(size_t)tg*128 + n], msg);
      }
    }
}

// ---- messages GEMV (tiers 0/1, r12-proven)
__global__ __launch_bounds__(256) void messages_v14f(
    const float* __restrict__ x, const float* __restrict__ ea,
    const int* __restrict__ eidx,
    const float* __restrict__ W_V,  const float* __restrict__ b_V,
    const float* __restrict__ W_Ev, const float* __restrict__ b_Ev,
    const float* __restrict__ scores, const unsigned* __restrict__ segmax,
    const float* __restrict__ segsum, float* __restrict__ agg)
{
  __shared__ float eaT[128][16], xsT[128][16];
  __shared__ int sIdx[16], tIdx[16];

  const int tid = threadIdx.x;
  const int e0  = blockIdx.x * 16;

  if (tid < 16){
    sIdx[tid] = eidx[e0 + tid];
    tIdx[tid] = eidx[N_EDGES + e0 + tid];
  }
  __syncthreads();

  for (int idx = tid; idx < 16*128; idx += 256){
    int r = idx >> 7, k = idx & 127;
    eaT[k][r] = ea[(size_t)(e0 + r)*128 + k];
    xsT[k][r] = x[(size_t)sIdx[r]*128 + k];
  }
  __syncthreads();

  const int j  = tid & 127;
  const int h8 = (tid >> 7) * 8;

  float av[8], ae[8];
  #pragma unroll
  for (int i=0;i<8;i++){ av[i]=0.f; ae[i]=0.f; }

  for (int k=0;k<128;k++){
    const float wv = W_V[(size_t)k*128 + j];
    const float we = W_Ev[(size_t)k*128 + j];
    const float4 s0 = *reinterpret_cast<const float4*>(&xsT[k][h8]);
    const float4 s1 = *reinterpret_cast<const float4*>(&xsT[k][h8+4]);
    const float4 e0v = *reinterpret_cast<const float4*>(&eaT[k][h8]);
    const float4 e1v = *reinterpret_cast<const float4*>(&eaT[k][h8+4]);
    const float sv[8] = {s0.x,s0.y,s0.z,s0.w,s1.x,s1.y,s1.z,s1.w};
    const float ev[8] = {e0v.x,e0v.y,e0v.z,e0v.w,e1v.x,e1v.y,e1v.z,e1v.w};
    #pragma unroll
    for (int i=0;i<8;i++){
      av[i] = fmaf(sv[i], wv, av[i]);
      ae[i] = fmaf(ev[i], we, ae[i]);
    }
  }

  const float bv = b_V[j], be = b_Ev[j];
  const int h = j >> 4;
  #pragma unroll
  for (int i=0;i<8;i++){
    const int el = h8 + i;
    const size_t e = (size_t)e0 + el;
    const int t = tIdx[el];
    const float m   = funmap(segmax[(size_t)t*8 + h]);
    const float d   = segsum[(size_t)t*8 + h] + 1e-16f;
    const float a   = expf(scores[e*8 + h] - m) / d;
    const float msg = san(((av[i] + bv) + (ae[i] + be)) * a);
    atomicAdd(&agg[(size_t)t*128 + j], msg);
  }
}

// ---- x_out = agg @ W_O + b_O (r16-proven)
__global__ __launch_bounds__(256) void oproj_v19(const float* __restrict__ agg,
    const float* __restrict__ W, const float* __restrict__ bias,
    float* __restrict__ outx)
{
  __shared__ float AT[128][32];
  const int tid  = threadIdx.x;
  const int base = blockIdx.x * 32;

  for (int idx = tid; idx < 32*128; idx += 256){
    int r = idx >> 7, k = idx & 127;
    AT[k][r] = agg[(size_t)(base + r)*128 + k];
  }
  __syncthreads();

  const int j  = tid & 127;
  const int rb = (tid >> 7) * 16;
  float acc[16];
  #pragma unroll
  for (int i=0;i<16;i++) acc[i] = 0.f;

  for (int k=0;k<128;k++){
    const float w = W[(size_t)k*128 + j];
    const float4 a0 = *reinterpret_cast<const float4*>(&AT[k][rb]);
    const float4 a1 = *reinterpret_cast<const float4*>(&AT[k][rb+4]);
    const float4 a2 = *reinterpret_cast<const float4*>(&AT[k][rb+8]);
    const float4 a3 = *reinterpret_cast<const float4*>(&AT[k][rb+12]);
    const float avv[16] = {a0.x,a0.y,a0.z,a0.w,a1.x,a1.y,a1.z,a1.w,
                           a2.x,a2.y,a2.z,a2.w,a3.x,a3.y,a3.z,a3.w};
    #pragma unroll
    for (int i=0;i<16;i++) acc[i] = fmaf(avv[i], w, acc[i]);
  }

  const float bj = bias[j];
  #pragma unroll
  for (int i=0;i<16;i++)
    outx[(size_t)(base + rb + i)*128 + j] = san(acc[i] + bj);
}

// ---- tier-0 fallback front (r14-proven)
template<bool PREPPED>
__global__ __launch_bounds__(256) void front_v14f(
    const float* __restrict__ x, const float* __restrict__ ea,
    const int* __restrict__ eidx,
    const float* __restrict__ W_Q, const float* __restrict__ b_Q,
    const float* __restrict__ W_K, const float* __restrict__ b_K,
    const float* __restrict__ W_Ew, const float* __restrict__ b_Ew,
    const float* __restrict__ W_Eb, const float* __restrict__ b_Eb,
    const float* __restrict__ b_A,
    const float* __restrict__ W_Eo, const float* __restrict__ b_Eo,
    const short* __restrict__ wsw,
    float* __restrict__ scores, unsigned* __restrict__ segmax,
    float* __restrict__ oute, int eo_min)
{
  __shared__ __align__(16) short AFh[3][2048];
  __shared__ __align__(16) short AFl[3][2048];
  __shared__ int sIdx[16], tIdx[16];

  const int tid = threadIdx.x;
  const int e0  = blockIdx.x * 16;

  if (tid < 16){
    sIdx[tid] = eidx[e0 + tid];
    tIdx[tid] = eidx[N_EDGES + e0 + tid];
  }
  __syncthreads();

  {
    const int r = tid & 15, c = tid >> 4;
    const int off = (c*16 + r)*8;
    stage_row(x  + (size_t)sIdx[r]*128 + c*8, &AFh[0][off], &AFl[0][off]);
    stage_row(x  + (size_t)tIdx[r]*128 + c*8, &AFh[1][off], &AFl[1][off]);
    stage_row(ea + (size_t)(e0 + r)*128 + c*8, &AFh[2][off], &AFl[2][off]);
  }
  __syncthreads();

  const int wv = tid >> 6;
  const int mi = (tid & 63) & 15;
  const int kg = (tid & 63) >> 4;

  f32x4 aq[2], ak[2], aw[2], ab[2];
  #pragma unroll
  for (int t = 0; t < 2; ++t){
    aq[t] = (f32x4){0,0,0,0}; ak[t] = (f32x4){0,0,0,0};
    aw[t] = (f32x4){0,0,0,0}; ab[t] = (f32x4){0,0,0,0};
  }

  #pragma unroll
  for (int ks = 0; ks < 4; ++ks){
    const int ao = ((ks*4 + kg)*16 + mi)*8;
    const short8 xh = *reinterpret_cast<const short8*>(&AFh[0][ao]);
    const short8 xl = *reinterpret_cast<const short8*>(&AFl[0][ao]);
    const short8 th = *reinterpret_cast<const short8*>(&AFh[1][ao]);
    const short8 tl = *reinterpret_cast<const short8*>(&AFl[1][ao]);
    const short8 eh = *reinterpret_cast<const short8*>(&AFh[2][ao]);
    const short8 el = *reinterpret_cast<const short8*>(&AFl[2][ao]);
    const int kb = ks*32 + kg*8;

    #pragma unroll
    for (int t = 0; t < 2; ++t){
      const int n = (wv*2 + t)*16 + mi;
      short8 qh, ql, kh, kl, wh, wl, bh, bl;
      if (PREPPED){
        qh = *reinterpret_cast<const short8*>(&wsw[OFF_WQ  + n*128 + kb]);
        ql = *reinterpret_cast<const short8*>(&wsw[OFF_WQ  + WT_SZ + n*128 + kb]);
        kh = *reinterpret_cast<const short8*>(&wsw[OFF_WK  + n*128 + kb]);
        kl = *reinterpret_cast<const short8*>(&wsw[OFF_WK  + WT_SZ + n*128 + kb]);
        wh = *reinterpret_cast<const short8*>(&wsw[OFF_WEW + n*128 + kb]);
        wl = *reinterpret_cast<const short8*>(&wsw[OFF_WEW + WT_SZ + n*128 + kb]);
        bh = *reinterpret_cast<const short8*>(&wsw[OFF_WEB + n*128 + kb]);
        bl = *reinterpret_cast<const short8*>(&wsw[OFF_WEB + WT_SZ + n*128 + kb]);
      } else {
        #pragma unroll
        for (int q = 0; q < 8; ++q){
          short h, l;
          split(W_Q [(size_t)(kb + q)*128 + n], h, l); qh[q] = h; ql[q] = l;
          split(W_K [(size_t)(kb + q)*128 + n], h, l); kh[q] = h; kl[q] = l;
          split(W_Ew[(size_t)(kb + q)*128 + n], h, l); wh[q] = h; wl[q] = l;
          split(W_Eb[(size_t)(kb + q)*128 + n], h, l); bh[q] = h; bl[q] = l;
        }
      }
      aq[t] = __builtin_amdgcn_mfma_f32_16x16x32_bf16(xh, qh, aq[t], 0,0,0);
      ak[t] = __builtin_amdgcn_mfma_f32_16x16x32_bf16(th, kh, ak[t], 0,0,0);
      aw[t] = __builtin_amdgcn_mfma_f32_16x16x32_bf16(eh, wh, aw[t], 0,0,0);
      ab[t] = __builtin_amdgcn_mfma_f32_16x16x32_bf16(eh, bh, ab[t], 0,0,0);
      aq[t] = __builtin_amdgcn_mfma_f32_16x16x32_bf16(xl, qh, aq[t], 0,0,0);
      ak[t] = __builtin_amdgcn_mfma_f32_16x16x32_bf16(tl, kh, ak[t], 0,0,0);
      aw[t] = __builtin_amdgcn_mfma_f32_16x16x32_bf16(el, wh, aw[t], 0,0,0);
      ab[t] = __builtin_amdgcn_mfma_f32_16x16x32_bf16(el, bh, ab[t], 0,0,0);
      aq[t] = __builtin_amdgcn_mfma_f32_16x16x32_bf16(xh, ql, aq[t], 0,0,0);
      ak[t] = __builtin_amdgcn_mfma_f32_16x16x32_bf16(th, kl, ak[t], 0,0,0);
      aw[t] = __builtin_amdgcn_mfma_f32_16x16x32_bf16(eh, wl, aw[t], 0,0,0);
      ab[t] = __builtin_amdgcn_mfma_f32_16x16x32_bf16(eh, bl, ab[t], 0,0,0);
    }
  }

  short afh[2][4], afl[2][4];
  #pragma unroll
  for (int t = 0; t < 2; ++t){
    const int n = (wv*2 + t)*16 + mi;
    const float bqk = b_Q[n] + b_K[n];
    const float bw  = b_Ew[n];
    const float bb  = b_Eb[n];
    #pragma unroll
    for (int q = 0; q < 4; ++q){
      const float qk = aq[t][q] + ak[t][q] + bqk;
      const float ew = aw[t][q] + bw;
      const float eb = ab[t][q] + bb;
      const float pre = qk * ew;
      const float ssv = pre > 0.f ?  sqrtf( pre + 1e-8f)
                      : (pre < 0.f ? -sqrtf(-pre + 1e-8f) : 0.f);
      const float af = fmaxf(ssv + eb, 0.f);
      short hh, ll; split(af, hh, ll);
      afh[t][q] = hh; afl[t][q] = ll;
    }
  }
  __syncthreads();

  #pragma unroll
  for (int t = 0; t < 2; ++t){
    const int c  = (wv*2 + t)*2 + (mi >> 3);
    const int k7 = mi & 7;
    #pragma unroll
    for (int q = 0; q < 4; ++q){
      const int idx = (c*16 + kg*4 + q)*8 + k7;
      AFh[0][idx] = afh[t][q];
      AFl[0][idx] = afl[t][q];
    }
  }
  __syncthreads();

  if (PREPPED && wv == 0){
    f32x4 acc = {0,0,0,0};
    #pragma unroll
    for (int ks = 0; ks < 4; ++ks){
      const int kb = ks*32 + kg*8;
      const int ao = ((ks*4 + kg)*16 + mi)*8;
      const short8 ah = *reinterpret_cast<const short8*>(&AFh[0][ao]);
      const short8 al = *reinterpret_cast<const short8*>(&AFl[0][ao]);
      const short8 bh = *reinterpret_cast<const short8*>(&wsw[OFF_WA + mi*128 + kb]);
      const short8 bl = *reinterpret_cast<const short8*>(&wsw[OFF_WA + 2048 + mi*128 + kb]);
      acc = __builtin_amdgcn_mfma_f32_16x16x32_bf16(ah, bh, acc, 0,0,0);
      acc = __builtin_amdgcn_mfma_f32_16x16x32_bf16(al, bh, acc, 0,0,0);
      acc = __builtin_amdgcn_mfma_f32_16x16x32_bf16(ah, bl, acc, 0,0,0);
    }
    if (mi < 8){
      const float ba = b_A[mi];
      #pragma unroll
      for (int q = 0; q < 4; ++q){
        const int er = kg*4 + q;
        const float s = san(acc[q] + ba);
        scores[(size_t)(e0 + er)*8 + mi] = s;
        atomicMax(&segmax[(size_t)tIdx[er]*8 + mi], fmap(s));
      }
    }
  }

  if (e0 >= eo_min){
    #pragma unroll
    for (int t2 = 0; t2 < 2; ++t2){
      const int n = (wv*2 + t2)*16 + mi;
      f32x4 acc = {0,0,0,0};
      #pragma unroll
      for (int ks = 0; ks < 4; ++ks){
        const int kb = ks*32 + kg*8;
        const int ao = ((ks*4 + kg)*16 + mi)*8;
        const short8 ah = *reinterpret_cast<const short8*>(&AFh[0][ao]);
        const short8 al = *reinterpret_cast<const short8*>(&AFl[0][ao]);
        short8 bh, bl;
        if (PREPPED){
          bh = *reinterpret_cast<const short8*>(&wsw[OFF_WEO + n*128 + kb]);
          bl = *reinterpret_cast<const short8*>(&wsw[OFF_WEO + WT_SZ + n*128 + kb]);
        } else {
          #pragma unroll
          for (int q = 0; q < 8; ++q){
            short h, l; split(W_Eo[(size_t)(kb + q)*128 + n], h, l); bh[q] = h; bl[q] = l;
          }
        }
        acc = __builtin_amdgcn_mfma_f32_16x16x32_bf16(ah, bh, acc, 0,0,0);
        acc = __builtin_amdgcn_mfma_f32_16x16x32_bf16(al, bh, acc, 0,0,0);
        acc = __builtin_amdgcn_mfma_f32_16x16x32_bf16(ah, bl, acc, 0,0,0);
      }
      const float be = b_Eo[n];
      #pragma unroll
      for (int q = 0; q < 4; ++q)
        oute[(size_t)(e0 + kg*4 + q)*128 + n] = san(acc[q] + be);
    }
  }
}

extern "C" void kernel_launch(void* const* d_in, const int* in_sizes, int n_in,
                              void* d_out, int out_size, void* d_ws, size_t ws_size,
                              hipStream_t stream)
{
  (void)in_sizes; (void)n_in; (void)out_size;
  const float* x    = (const float*)d_in[0];
  const float* ea   = (const float*)d_in[1];
  const int*   eidx = (const int*)d_in[2];
  const float* W_Q  = (const float*)d_in[4];  const float* b_Q  = (const float*)d_in[5];
  const float* W_K  = (const float*)d_in[6];  const float* b_K  = (const float*)d_in[7];
  const float* W_V  = (const float*)d_in[8];  const float* b_V  = (const float*)d_in[9];
  const float* W_Ew = (const float*)d_in[10]; const float* b_Ew = (const float*)d_in[11];
  const float* W_Eb = (const float*)d_in[12]; const float* b_Eb = (const float*)d_in[13];
  const float* W_Ev = (const float*)d_in[14]; const float* b_Ev = (const float*)d_in[15];
  const float* W_O  = (const float*)d_in[16]; const float* b_O  = (const float*)d_in[17];
  const float* W_Eo = (const float*)d_in[18]; const float* b_Eo = (const float*)d_in[19];
  const float* W_A  = (const float*)d_in[20]; const float* b_A  = (const float*)d_in[21];

  float* out_x = (float*)d_out;
  float* oute  = out_x + OUT_E_ELEM;

  float*    scores = (float*)d_out;
  unsigned* segmax = (unsigned*)((char*)d_out + SCORES_B);
  float*    segsum = (float*)((char*)d_out + SCORES_B + SEG_B);

  const size_t SZ_NODEF = (size_t)N_NODES*128*4;       // 51.2 MB
  const size_t NEED_QK   = 2*SZ_NODEF + WSW_BYTES;     // ~102.9 MB
  const size_t NEED_FULL = 3*SZ_NODEF + WSW_BYTES;     // ~154.1 MB

  const int tier = (ws_size >= NEED_FULL) ? 2 : (ws_size >= NEED_QK) ? 1 : 0;

  dim3 blk(256);
  hipMemsetAsync((void*)segmax, 0, 2*SEG_B, stream);

  if (tier >= 1){
    char*  ws  = (char*)d_ws;
    float* Qn  = (float*)ws;
    float* Kn  = (float*)(ws + SZ_NODEF);
    float* Vn  = (tier == 2) ? (float*)(ws + 2*SZ_NODEF) : nullptr;
    short* wsw = (short*)(ws + ((tier == 2) ? 3 : 2)*SZ_NODEF);
    float* agg = Qn;    // Qn dead after front

    prep_v19<<<dim3(912), dim3(128), 0, stream>>>(W_Q, W_K, W_Ew, W_Eb, W_Eo, W_V, W_Ev, W_A, wsw);

    nodeproj_v19<<<dim3(N_NODES/32), blk, 0, stream>>>(x, wsw, b_Q, b_K, b_V,
        Qn, Kn, Vn, tier == 2 ? 1 : 0);

    front_qk_v19<<<dim3(N_EDGES/32), blk, 0, stream>>>(ea, eidx, Qn, Kn,
        b_Ew, b_Eb, b_A, b_Eo, wsw, scores, segmax, oute, 1);

    hipMemsetAsync((void*)agg, 0, AGG_BYTES, stream);

    seg_sum_v19<<<dim3((N_EDGES*8 + 255)/256), blk, 0, stream>>>(scores, eidx, segmax, segsum);

    if (tier == 2)
      messages_mfma_v19<<<dim3(N_EDGES/32), blk, 0, stream>>>(ea, eidx, Vn, b_Ev,
          wsw, scores, segmax, segsum, agg);
    else
      messages_v14f<<<dim3(N_EDGES/16), blk, 0, stream>>>(x, ea, eidx,
          W_V, b_V, W_Ev, b_Ev, scores, segmax, segsum, agg);

    oproj_v19<<<dim3(N_NODES/32), blk, 0, stream>>>(agg, W_O, b_O, out_x);

  } else {
    // ---- tier 0 fallback: r14-proven pipeline; wsw + agg inside d_out ----
    short* wsw = (short*)((char*)d_out + WSW_OFF);
    float* agg = oute;                             // rows [0, EO_MIN)

    hipMemsetAsync((void*)agg, 0, AGG_BYTES, stream);

    prep_v19<<<dim3(912), dim3(128), 0, stream>>>(W_Q, W_K, W_Ew, W_Eb, W_Eo, W_V, W_Ev, W_A, wsw);

    front_v14f<true><<<dim3(N_EDGES/16), blk, 0, stream>>>(x, ea, eidx,
        W_Q, b_Q, W_K, b_K, W_Ew, b_Ew, W_Eb, b_Eb, b_A, W_Eo, b_Eo, wsw,
        scores, segmax, oute, EO_MIN);

    seg_sum_v19<<<dim3((N_EDGES*8 + 255)/256), blk, 0, stream>>>(scores, eidx, segmax, segsum);

    messages_v14f<<<dim3(N_EDGES/16), blk, 0, stream>>>(x, ea, eidx,
        W_V, b_V, W_Ev, b_Ev, scores, segmax, segsum, agg);

    oproj_v19<<<dim3(N_NODES/32), blk, 0, stream>>>(agg, W_O, b_O, out_x);

    front_v14f<false><<<dim3(EO_MIN/16), blk, 0, stream>>>(x, ea, eidx,
        W_Q, b_Q, W_K, b_K, W_Ew, b_Ew, W_Eb, b_Eb, b_A, W_Eo, b_Eo, nullptr,
        nullptr, nullptr, oute, 0);
  }
}

// Round 20
// 907.283 us; speedup vs baseline: 1.1432x; 1.1028x over previous
//
#include <hip/hip_runtime.h>
#include <hip/hip_bf16.h>

typedef __hip_bfloat16 bf16;

#define N_NODES 100000
#define N_EDGES 400000
#define EO_MIN  100000   // tier-0 fallback only

// ---- f32 geometry of d_out (proven r12-r19) ----
#define OUT_E_ELEM ((size_t)N_NODES*128)
#define SCORES_B   ((size_t)N_EDGES*8*4)            // 12.8 MB (fallback tiers)
#define SEG_B      ((size_t)N_NODES*8*4)            //  3.2 MB
#define AGG_BYTES  ((size_t)N_NODES*128*4)          // 51.2 MB
#define WSW_OFF    (SCORES_B + 2*SEG_B)             // fallback wsw inside d_out

// prepped-weight tables (shorts): WT[n][k] transposed, hi then lo.
#define WT_SZ   16384
#define OFF_WQ  (0*WT_SZ)
#define OFF_WK  (2*WT_SZ)
#define OFF_WEW (4*WT_SZ)
#define OFF_WEB (6*WT_SZ)
#define OFF_WEO (8*WT_SZ)
#define OFF_WV  (10*WT_SZ)
#define OFF_WEV (12*WT_SZ)
#define OFF_WA  (14*WT_SZ)    // 16x128 padded, hi + lo(+2048)
#define WSW_SHORTS (14*WT_SZ + 2*2048)
#define WSW_BYTES  ((size_t)WSW_SHORTS*2)

using short8 = __attribute__((ext_vector_type(8))) short;
using f32x4  = __attribute__((ext_vector_type(4))) float;

__device__ __forceinline__ float b2f(bf16 v){ return __bfloat162float(v); }
__device__ __forceinline__ bf16  f2b(float v){ return __float2bfloat16(v); }
__device__ __forceinline__ short bits(bf16 v){ short s; __builtin_memcpy(&s, &v, 2); return s; }
__device__ __forceinline__ void split(float v, short& h, short& l){
  bf16 hb = f2b(v);
  h = bits(hb);
  l = bits(f2b(v - b2f(hb)));
}
__device__ __forceinline__ float san(float v){
  return (v == v && fabsf(v) < 1e30f) ? v : 0.f;
}
__device__ __forceinline__ unsigned fmap(float f){
  unsigned u = __float_as_uint(f);
  return (u & 0x80000000u) ? ~u : (u | 0x80000000u);
}
__device__ __forceinline__ float funmap(unsigned u){
  unsigned b = (u & 0x80000000u) ? (u ^ 0x80000000u) : ~u;
  return __uint_as_float(b);
}

// ---- unified weight prep (r16-proven)
__global__ void prep_v20(const float* __restrict__ W_Q, const float* __restrict__ W_K,
                         const float* __restrict__ W_Ew, const float* __restrict__ W_Eb,
                         const float* __restrict__ W_Eo, const float* __restrict__ W_V,
                         const float* __restrict__ W_Ev, const float* __restrict__ W_A,
                         short* __restrict__ wsw)
{
  const int b = blockIdx.x;
  if (b < 896){
    const int mi = b >> 7, n = b & 127;
    const float* W = (mi==0)?W_Q:(mi==1)?W_K:(mi==2)?W_Ew:(mi==3)?W_Eb:(mi==4)?W_Eo:(mi==5)?W_V:W_Ev;
    short* dh = wsw + mi*2*WT_SZ;
    short* dl = dh + WT_SZ;
    for (int k = threadIdx.x; k < 128; k += 128){
      short h, l; split(W[(size_t)k*128 + n], h, l);
      dh[n*128 + k] = h; dl[n*128 + k] = l;
    }
  } else {
    const int n = b - 896;
    short* dh = wsw + OFF_WA;
    short* dl = dh + 2048;
    for (int k = threadIdx.x; k < 128; k += 128){
      float v = (n < 8) ? W_A[(size_t)k*8 + n] : 0.f;
      short h, l; split(v, h, l);
      dh[n*128 + k] = h; dl[n*128 + k] = l;
    }
  }
}

__device__ __forceinline__ void stage_row(const float* __restrict__ src,
                                          short* __restrict__ dh, short* __restrict__ dl){
  const float4 v0 = *reinterpret_cast<const float4*>(src);
  const float4 v1 = *reinterpret_cast<const float4*>(src + 4);
  const float vv[8] = {v0.x, v0.y, v0.z, v0.w, v1.x, v1.y, v1.z, v1.w};
  short8 h, l;
  #pragma unroll
  for (int q = 0; q < 8; ++q){ short hh, ll; split(vv[q], hh, ll); h[q] = hh; l[q] = ll; }
  *reinterpret_cast<short8*>(dh) = h;
  *reinterpret_cast<short8*>(dl) = l;
}

// ---- nodeproj (r15/r16-proven)
__global__ __launch_bounds__(256) void nodeproj_v20(
    const float* __restrict__ x, const short* __restrict__ wsw,
    const float* __restrict__ b_Q, const float* __restrict__ b_K,
    const float* __restrict__ b_V,
    float* __restrict__ Qn, float* __restrict__ Kn, float* __restrict__ Vn,
    int do_v)
{
  __shared__ __align__(16) short Xh[2][2048], Xl[2][2048];
  const int tid = threadIdx.x;
  const int n0  = blockIdx.x * 32;

  {
    const int r = tid & 15, c = tid >> 4;
    #pragma unroll
    for (int rg = 0; rg < 2; ++rg)
      stage_row(x + (size_t)(n0 + rg*16 + r)*128 + c*8,
                &Xh[rg][(c*16 + r)*8], &Xl[rg][(c*16 + r)*8]);
  }
  __syncthreads();

  const int wv = tid >> 6;
  const int mi = (tid & 63) & 15;
  const int kg = (tid & 63) >> 4;

  f32x4 aQ[2][2], aK[2][2], aV[2][2];
  #pragma unroll
  for (int rg = 0; rg < 2; ++rg)
    #pragma unroll
    for (int t = 0; t < 2; ++t){
      aQ[rg][t] = (f32x4){0,0,0,0}; aK[rg][t] = (f32x4){0,0,0,0}; aV[rg][t] = (f32x4){0,0,0,0};
    }

  #pragma unroll
  for (int ks = 0; ks < 4; ++ks){
    const int ao = ((ks*4 + kg)*16 + mi)*8;
    const int kb = ks*32 + kg*8;
    short8 xh[2], xl[2];
    #pragma unroll
    for (int rg = 0; rg < 2; ++rg){
      xh[rg] = *reinterpret_cast<const short8*>(&Xh[rg][ao]);
      xl[rg] = *reinterpret_cast<const short8*>(&Xl[rg][ao]);
    }
    #pragma unroll
    for (int t = 0; t < 2; ++t){
      const int n = (wv*2 + t)*16 + mi;
      const short8 qh = *reinterpret_cast<const short8*>(&wsw[OFF_WQ + n*128 + kb]);
      const short8 ql = *reinterpret_cast<const short8*>(&wsw[OFF_WQ + WT_SZ + n*128 + kb]);
      const short8 kh = *reinterpret_cast<const short8*>(&wsw[OFF_WK + n*128 + kb]);
      const short8 kl = *reinterpret_cast<const short8*>(&wsw[OFF_WK + WT_SZ + n*128 + kb]);
      const short8 vh = *reinterpret_cast<const short8*>(&wsw[OFF_WV + n*128 + kb]);
      const short8 vl = *reinterpret_cast<const short8*>(&wsw[OFF_WV + WT_SZ + n*128 + kb]);
      #pragma unroll
      for (int rg = 0; rg < 2; ++rg){
        aQ[rg][t] = __builtin_amdgcn_mfma_f32_16x16x32_bf16(xh[rg], qh, aQ[rg][t], 0,0,0);
        aK[rg][t] = __builtin_amdgcn_mfma_f32_16x16x32_bf16(xh[rg], kh, aK[rg][t], 0,0,0);
        aQ[rg][t] = __builtin_amdgcn_mfma_f32_16x16x32_bf16(xl[rg], qh, aQ[rg][t], 0,0,0);
        aK[rg][t] = __builtin_amdgcn_mfma_f32_16x16x32_bf16(xl[rg], kh, aK[rg][t], 0,0,0);
        aQ[rg][t] = __builtin_amdgcn_mfma_f32_16x16x32_bf16(xh[rg], ql, aQ[rg][t], 0,0,0);
        aK[rg][t] = __builtin_amdgcn_mfma_f32_16x16x32_bf16(xh[rg], kl, aK[rg][t], 0,0,0);
        if (do_v){
          aV[rg][t] = __builtin_amdgcn_mfma_f32_16x16x32_bf16(xh[rg], vh, aV[rg][t], 0,0,0);
          aV[rg][t] = __builtin_amdgcn_mfma_f32_16x16x32_bf16(xl[rg], vh, aV[rg][t], 0,0,0);
          aV[rg][t] = __builtin_amdgcn_mfma_f32_16x16x32_bf16(xh[rg], vl, aV[rg][t], 0,0,0);
        }
      }
    }
  }

  #pragma unroll
  for (int rg = 0; rg < 2; ++rg)
    #pragma unroll
    for (int t = 0; t < 2; ++t){
      const int n = (wv*2 + t)*16 + mi;
      const float bq = b_Q[n], bk = b_K[n], bv = b_V[n];
      #pragma unroll
      for (int q = 0; q < 4; ++q){
        const size_t row = n0 + rg*16 + kg*4 + q;
        Qn[row*128 + n] = aQ[rg][t][q] + bq;
        Kn[row*128 + n] = aK[rg][t][q] + bk;
        if (do_v) Vn[row*128 + n] = aV[rg][t][q] + bv;
      }
    }
}

// ---- FUSED front (tier 3): Ew/Eb/Ev MFMA + af + direct-exp scores + den/agg
// accumulation (messages) + Eo. No scores/segmax/seg_sum/messages kernels.
// agg lives at out_x (in-place oproj); den in ws tail. alpha fold r18-proven.
__global__ __launch_bounds__(256) void front_fused_v20(
    const float* __restrict__ ea, const int* __restrict__ eidx,
    const float* __restrict__ Qn, const float* __restrict__ Kn,
    const float* __restrict__ Vn,
    const float* __restrict__ b_Ew, const float* __restrict__ b_Eb,
    const float* __restrict__ b_A,  const float* __restrict__ b_Eo,
    const float* __restrict__ b_Ev,
    const short* __restrict__ wsw,
    float* __restrict__ den, float* __restrict__ agg,
    float* __restrict__ oute)
{
  __shared__ __align__(16) char smem[16384];
  __shared__ float exps[32][8];
  __shared__ int sIdx[32], tIdx[32];
  short* AFh = (short*)smem;            // [2][2048]
  short* AFl = (short*)(smem + 8192);   // [2][2048]
  float* qkf = (float*)smem;            // [32][128] (aliases AFh/AFl)

  const int tid = threadIdx.x;
  const int e0  = blockIdx.x * 32;

  if (tid < 32){
    sIdx[tid] = eidx[e0 + tid];
    tIdx[tid] = eidx[N_EDGES + e0 + tid];
  }
  {
    const int r = tid & 15, c = tid >> 4;
    #pragma unroll
    for (int rg = 0; rg < 2; ++rg)
      stage_row(ea + (size_t)(e0 + rg*16 + r)*128 + c*8,
                &AFh[rg*2048 + (c*16 + r)*8], &AFl[rg*2048 + (c*16 + r)*8]);
  }
  __syncthreads();

  const int wv = tid >> 6;
  const int mi = (tid & 63) & 15;
  const int kg = (tid & 63) >> 4;

  // ---- phase 1: Ew, Eb, Ev via split MFMA
  f32x4 aw[2][2], ab[2][2], aev[2][2];
  #pragma unroll
  for (int rg = 0; rg < 2; ++rg)
    #pragma unroll
    for (int t = 0; t < 2; ++t){
      aw[rg][t] = (f32x4){0,0,0,0}; ab[rg][t] = (f32x4){0,0,0,0};
      aev[rg][t] = (f32x4){0,0,0,0};
    }

  #pragma unroll
  for (int ks = 0; ks < 4; ++ks){
    const int ao = ((ks*4 + kg)*16 + mi)*8;
    const int kb = ks*32 + kg*8;
    short8 eh[2], el_[2];
    #pragma unroll
    for (int rg = 0; rg < 2; ++rg){
      eh[rg]  = *reinterpret_cast<const short8*>(&AFh[rg*2048 + ao]);
      el_[rg] = *reinterpret_cast<const short8*>(&AFl[rg*2048 + ao]);
    }
    #pragma unroll
    for (int t = 0; t < 2; ++t){
      const int n = (wv*2 + t)*16 + mi;
      const short8 wh = *reinterpret_cast<const short8*>(&wsw[OFF_WEW + n*128 + kb]);
      const short8 wl = *reinterpret_cast<const short8*>(&wsw[OFF_WEW + WT_SZ + n*128 + kb]);
      const short8 bh = *reinterpret_cast<const short8*>(&wsw[OFF_WEB + n*128 + kb]);
      const short8 bl = *reinterpret_cast<const short8*>(&wsw[OFF_WEB + WT_SZ + n*128 + kb]);
      const short8 vh = *reinterpret_cast<const short8*>(&wsw[OFF_WEV + n*128 + kb]);
      const short8 vl = *reinterpret_cast<const short8*>(&wsw[OFF_WEV + WT_SZ + n*128 + kb]);
      #pragma unroll
      for (int rg = 0; rg < 2; ++rg){
        aw[rg][t]  = __builtin_amdgcn_mfma_f32_16x16x32_bf16(eh[rg], wh, aw[rg][t], 0,0,0);
        ab[rg][t]  = __builtin_amdgcn_mfma_f32_16x16x32_bf16(eh[rg], bh, ab[rg][t], 0,0,0);
        aev[rg][t] = __builtin_amdgcn_mfma_f32_16x16x32_bf16(eh[rg], vh, aev[rg][t], 0,0,0);
        aw[rg][t]  = __builtin_amdgcn_mfma_f32_16x16x32_bf16(el_[rg], wh, aw[rg][t], 0,0,0);
        ab[rg][t]  = __builtin_amdgcn_mfma_f32_16x16x32_bf16(el_[rg], bh, ab[rg][t], 0,0,0);
        aev[rg][t] = __builtin_amdgcn_mfma_f32_16x16x32_bf16(el_[rg], vh, aev[rg][t], 0,0,0);
        aw[rg][t]  = __builtin_amdgcn_mfma_f32_16x16x32_bf16(eh[rg], wl, aw[rg][t], 0,0,0);
        ab[rg][t]  = __builtin_amdgcn_mfma_f32_16x16x32_bf16(eh[rg], bl, ab[rg][t], 0,0,0);
        aev[rg][t] = __builtin_amdgcn_mfma_f32_16x16x32_bf16(eh[rg], vl, aev[rg][t], 0,0,0);
      }
    }
  }
  __syncthreads();   // ea-frags dead; smem freed for qk

  // ---- qk gather (v18-proven: indices from smem, after phase-1)
  {
    const int r = tid >> 3, cg = tid & 7;
    const float* qp = Qn + (size_t)sIdx[r]*128 + cg*16;
    const float* kp = Kn + (size_t)tIdx[r]*128 + cg*16;
    #pragma unroll
    for (int p = 0; p < 4; ++p){
      const float4 qv = *reinterpret_cast<const float4*>(qp + p*4);
      const float4 kv = *reinterpret_cast<const float4*>(kp + p*4);
      float4 s; s.x = qv.x+kv.x; s.y = qv.y+kv.y; s.z = qv.z+kv.z; s.w = qv.w+kv.w;
      *reinterpret_cast<float4*>(&qkf[r*128 + cg*16 + p*4]) = s;
    }
  }
  __syncthreads();

  // ---- epilogue: af in registers (proven math)
  short afh[2][2][4], afl[2][2][4];
  #pragma unroll
  for (int rg = 0; rg < 2; ++rg)
    #pragma unroll
    for (int t = 0; t < 2; ++t){
      const int n = (wv*2 + t)*16 + mi;
      const float bw = b_Ew[n], bb = b_Eb[n];
      #pragma unroll
      for (int q = 0; q < 4; ++q){
        const float qkv = qkf[(rg*16 + kg*4 + q)*128 + n];
        const float ew  = aw[rg][t][q] + bw;
        const float eb  = ab[rg][t][q] + bb;
        const float pre = qkv * ew;
        const float ssv = pre > 0.f ?  sqrtf( pre + 1e-8f)
                        : (pre < 0.f ? -sqrtf(-pre + 1e-8f) : 0.f);
        const float af = fmaxf(ssv + eb, 0.f);
        short hh, ll; split(af, hh, ll);
        afh[rg][t][q] = hh; afl[rg][t][q] = ll;
      }
    }
  __syncthreads();   // qk reads done; smem freed for af-frags

  // ---- scatter af (proven address math)
  #pragma unroll
  for (int rg = 0; rg < 2; ++rg)
    #pragma unroll
    for (int t = 0; t < 2; ++t){
      const int c  = (wv*2 + t)*2 + (mi >> 3);
      const int k7 = mi & 7;
      #pragma unroll
      for (int q = 0; q < 4; ++q){
        const int idx = (c*16 + kg*4 + q)*8 + k7;
        AFh[rg*2048 + idx] = afh[rg][t][q];
        AFl[rg*2048 + idx] = afl[rg][t][q];
      }
    }
  __syncthreads();

  // ---- scores via MFMA (waves 0,1); direct exp (no max-subtract; |score|<~15);
  // exps -> LDS broadcast + den atomicAdd
  if (wv < 2){
    const int rg = wv;
    f32x4 acc = {0,0,0,0};
    #pragma unroll
    for (int ks = 0; ks < 4; ++ks){
      const int kb = ks*32 + kg*8;
      const int ao = ((ks*4 + kg)*16 + mi)*8;
      const short8 ah = *reinterpret_cast<const short8*>(&AFh[rg*2048 + ao]);
      const short8 al = *reinterpret_cast<const short8*>(&AFl[rg*2048 + ao]);
      const short8 bh = *reinterpret_cast<const short8*>(&wsw[OFF_WA + mi*128 + kb]);
      const short8 bl = *reinterpret_cast<const short8*>(&wsw[OFF_WA + 2048 + mi*128 + kb]);
      acc = __builtin_amdgcn_mfma_f32_16x16x32_bf16(ah, bh, acc, 0,0,0);
      acc = __builtin_amdgcn_mfma_f32_16x16x32_bf16(al, bh, acc, 0,0,0);
      acc = __builtin_amdgcn_mfma_f32_16x16x32_bf16(ah, bl, acc, 0,0,0);
    }
    if (mi < 8){
      const float ba = b_A[mi];
      #pragma unroll
      for (int q = 0; q < 4; ++q){
        const int er = rg*16 + kg*4 + q;
        const float ev = expf(san(acc[q] + ba));
        exps[er][mi] = ev;
        atomicAdd(&den[(size_t)tIdx[er]*8 + mi], ev);
      }
    }
  }
  __syncthreads();

  // ---- fused messages: msg = (Vn[src] + Ev + b_Ev) * exp(score); agg atomic
  #pragma unroll
  for (int rg = 0; rg < 2; ++rg)
    #pragma unroll
    for (int t = 0; t < 2; ++t){
      const int n = (wv*2 + t)*16 + mi;
      const int h = n >> 4;
      const float bev = b_Ev[n];
      #pragma unroll
      for (int q = 0; q < 4; ++q){
        const int row = rg*16 + kg*4 + q;
        const int s = sIdx[row], tg = tIdx[row];
        const float ew_ = exps[row][h];
        const float msg = san((Vn[(size_t)s*128 + n] + aev[rg][t][q] + bev) * ew_);
        atomicAdd(&agg[(size_t)tg*128 + n], msg);
      }
    }

  // ---- fused Eo = af @ W_Eo (all edges)
  #pragma unroll
  for (int rg = 0; rg < 2; ++rg)
    #pragma unroll
    for (int t2 = 0; t2 < 2; ++t2){
      const int n = (wv*2 + t2)*16 + mi;
      f32x4 acc = {0,0,0,0};
      #pragma unroll
      for (int ks = 0; ks < 4; ++ks){
        const int kb = ks*32 + kg*8;
        const int ao = ((ks*4 + kg)*16 + mi)*8;
        const short8 ah = *reinterpret_cast<const short8*>(&AFh[rg*2048 + ao]);
        const short8 al = *reinterpret_cast<const short8*>(&AFl[rg*2048 + ao]);
        const short8 bh = *reinterpret_cast<const short8*>(&wsw[OFF_WEO + n*128 + kb]);
        const short8 bl = *reinterpret_cast<const short8*>(&wsw[OFF_WEO + WT_SZ + n*128 + kb]);
        acc = __builtin_amdgcn_mfma_f32_16x16x32_bf16(ah, bh, acc, 0,0,0);
        acc = __builtin_amdgcn_mfma_f32_16x16x32_bf16(al, bh, acc, 0,0,0);
        acc = __builtin_amdgcn_mfma_f32_16x16x32_bf16(ah, bl, acc, 0,0,0);
      }
      const float be = b_Eo[n];
      #pragma unroll
      for (int q = 0; q < 4; ++q)
        oute[(size_t)(e0 + rg*16 + kg*4 + q)*128 + n] = san(acc[q] + be);
    }
}

// ---- x_out = (agg/den) @ W_O + b_O; IN-PLACE on out_x (agg==outx; each block
// stages its own 32 rows behind the barrier before writing them — r5-proven).
__global__ __launch_bounds__(256) void oproj_div_v20(const float* __restrict__ agg,
    const float* __restrict__ den,
    const float* __restrict__ W, const float* __restrict__ bias,
    float* __restrict__ outx)
{
  __shared__ float AT[128][32];
  const int tid  = threadIdx.x;
  const int base = blockIdx.x * 32;

  for (int idx = tid; idx < 32*128; idx += 256){
    int r = idx >> 7, k = idx & 127;
    float v = agg[(size_t)(base + r)*128 + k];
    v /= (den[(size_t)(base + r)*8 + (k >> 4)] + 1e-16f);
    AT[k][r] = v;
  }
  __syncthreads();

  const int j  = tid & 127;
  const int rb = (tid >> 7) * 16;
  float acc[16];
  #pragma unroll
  for (int i=0;i<16;i++) acc[i] = 0.f;

  for (int k=0;k<128;k++){
    const float w = W[(size_t)k*128 + j];
    const float4 a0 = *reinterpret_cast<const float4*>(&AT[k][rb]);
    const float4 a1 = *reinterpret_cast<const float4*>(&AT[k][rb+4]);
    const float4 a2 = *reinterpret_cast<const float4*>(&AT[k][rb+8]);
    const float4 a3 = *reinterpret_cast<const float4*>(&AT[k][rb+12]);
    const float avv[16] = {a0.x,a0.y,a0.z,a0.w,a1.x,a1.y,a1.z,a1.w,
                           a2.x,a2.y,a2.z,a2.w,a3.x,a3.y,a3.z,a3.w};
    #pragma unroll
    for (int i=0;i<16;i++) acc[i] = fmaf(avv[i], w, acc[i]);
  }

  const float bj = bias[j];
  #pragma unroll
  for (int i=0;i<16;i++)
    outx[(size_t)(base + rb + i)*128 + j] = san(acc[i] + bj);
}

// ======== r19-proven fallback chain (tiers 0/1/2), verbatim ========
__global__ __launch_bounds__(256) void front_qk_v19f(
    const float* __restrict__ ea, const int* __restrict__ eidx,
    const float* __restrict__ Qn, const float* __restrict__ Kn,
    const float* __restrict__ b_Ew, const float* __restrict__ b_Eb,
    const float* __restrict__ b_A,  const float* __restrict__ b_Eo,
    const short* __restrict__ wsw,
    float* __restrict__ scores, unsigned* __restrict__ segmax,
    float* __restrict__ oute, int do_score)
{
  __shared__ __align__(16) char smem[16384];
  __shared__ int sIdx[32], tIdx[32];
  short* AFh = (short*)smem;
  short* AFl = (short*)(smem + 8192);
  float* qkf = (float*)smem;

  const int tid = threadIdx.x;
  const int e0  = blockIdx.x * 32;

  if (tid < 32){
    sIdx[tid] = eidx[e0 + tid];
    tIdx[tid] = eidx[N_EDGES + e0 + tid];
  }
  {
    const int r = tid & 15, c = tid >> 4;
    #pragma unroll
    for (int rg = 0; rg < 2; ++rg)
      stage_row(ea + (size_t)(e0 + rg*16 + r)*128 + c*8,
                &AFh[rg*2048 + (c*16 + r)*8], &AFl[rg*2048 + (c*16 + r)*8]);
  }
  __syncthreads();

  const int wv = tid >> 6;
  const int mi = (tid & 63) & 15;
  const int kg = (tid & 63) >> 4;

  f32x4 aw[2][2], ab[2][2];
  #pragma unroll
  for (int rg = 0; rg < 2; ++rg)
    #pragma unroll
    for (int t = 0; t < 2; ++t){ aw[rg][t] = (f32x4){0,0,0,0}; ab[rg][t] = (f32x4){0,0,0,0}; }

  #pragma unroll
  for (int ks = 0; ks < 4; ++ks){
    const int ao = ((ks*4 + kg)*16 + mi)*8;
    const int kb = ks*32 + kg*8;
    short8 eh[2], el_[2];
    #pragma unroll
    for (int rg = 0; rg < 2; ++rg){
      eh[rg]  = *reinterpret_cast<const short8*>(&AFh[rg*2048 + ao]);
      el_[rg] = *reinterpret_cast<const short8*>(&AFl[rg*2048 + ao]);
    }
    #pragma unroll
    for (int t = 0; t < 2; ++t){
      const int n = (wv*2 + t)*16 + mi;
      const short8 wh = *reinterpret_cast<const short8*>(&wsw[OFF_WEW + n*128 + kb]);
      const short8 wl = *reinterpret_cast<const short8*>(&wsw[OFF_WEW + WT_SZ + n*128 + kb]);
      const short8 bh = *reinterpret_cast<const short8*>(&wsw[OFF_WEB + n*128 + kb]);
      const short8 bl = *reinterpret_cast<const short8*>(&wsw[OFF_WEB + WT_SZ + n*128 + kb]);
      #pragma unroll
      for (int rg = 0; rg < 2; ++rg){
        aw[rg][t] = __builtin_amdgcn_mfma_f32_16x16x32_bf16(eh[rg], wh, aw[rg][t], 0,0,0);
        ab[rg][t] = __builtin_amdgcn_mfma_f32_16x16x32_bf16(eh[rg], bh, ab[rg][t], 0,0,0);
        aw[rg][t] = __builtin_amdgcn_mfma_f32_16x16x32_bf16(el_[rg], wh, aw[rg][t], 0,0,0);
        ab[rg][t] = __builtin_amdgcn_mfma_f32_16x16x32_bf16(el_[rg], bh, ab[rg][t], 0,0,0);
        aw[rg][t] = __builtin_amdgcn_mfma_f32_16x16x32_bf16(eh[rg], wl, aw[rg][t], 0,0,0);
        ab[rg][t] = __builtin_amdgcn_mfma_f32_16x16x32_bf16(eh[rg], bl, ab[rg][t], 0,0,0);
      }
    }
  }
  __syncthreads();

  {
    const int r = tid >> 3, cg = tid & 7;
    const float* qp = Qn + (size_t)sIdx[r]*128 + cg*16;
    const float* kp = Kn + (size_t)tIdx[r]*128 + cg*16;
    #pragma unroll
    for (int p = 0; p < 4; ++p){
      const float4 qv = *reinterpret_cast<const float4*>(qp + p*4);
      const float4 kv = *reinterpret_cast<const float4*>(kp + p*4);
      float4 s; s.x = qv.x+kv.x; s.y = qv.y+kv.y; s.z = qv.z+kv.z; s.w = qv.w+kv.w;
      *reinterpret_cast<float4*>(&qkf[r*128 + cg*16 + p*4]) = s;
    }
  }
  __syncthreads();

  short afh[2][2][4], afl[2][2][4];
  #pragma unroll
  for (int rg = 0; rg < 2; ++rg)
    #pragma unroll
    for (int t = 0; t < 2; ++t){
      const int n = (wv*2 + t)*16 + mi;
      const float bw = b_Ew[n], bb = b_Eb[n];
      #pragma unroll
      for (int q = 0; q < 4; ++q){
        const float qkv = qkf[(rg*16 + kg*4 + q)*128 + n];
        const float ew  = aw[rg][t][q] + bw;
        const float eb  = ab[rg][t][q] + bb;
        const float pre = qkv * ew;
        const float ssv = pre > 0.f ?  sqrtf( pre + 1e-8f)
                        : (pre < 0.f ? -sqrtf(-pre + 1e-8f) : 0.f);
        const float af = fmaxf(ssv + eb, 0.f);
        short hh, ll; split(af, hh, ll);
        afh[rg][t][q] = hh; afl[rg][t][q] = ll;
      }
    }
  __syncthreads();

  #pragma unroll
  for (int rg = 0; rg < 2; ++rg)
    #pragma unroll
    for (int t = 0; t < 2; ++t){
      const int c  = (wv*2 + t)*2 + (mi >> 3);
      const int k7 = mi & 7;
      #pragma unroll
      for (int q = 0; q < 4; ++q){
        const int idx = (c*16 + kg*4 + q)*8 + k7;
        AFh[rg*2048 + idx] = afh[rg][t][q];
        AFl[rg*2048 + idx] = afl[rg][t][q];
      }
    }
  __syncthreads();

  if (do_score && wv < 2){
    const int rg = wv;
    f32x4 acc = {0,0,0,0};
    #pragma unroll
    for (int ks = 0; ks < 4; ++ks){
      const int kb = ks*32 + kg*8;
      const int ao = ((ks*4 + kg)*16 + mi)*8;
      const short8 ah = *reinterpret_cast<const short8*>(&AFh[rg*2048 + ao]);
      const short8 al = *reinterpret_cast<const short8*>(&AFl[rg*2048 + ao]);
      const short8 bh = *reinterpret_cast<const short8*>(&wsw[OFF_WA + mi*128 + kb]);
      const short8 bl = *reinterpret_cast<const short8*>(&wsw[OFF_WA + 2048 + mi*128 + kb]);
      acc = __builtin_amdgcn_mfma_f32_16x16x32_bf16(ah, bh, acc, 0,0,0);
      acc = __builtin_amdgcn_mfma_f32_16x16x32_bf16(al, bh, acc, 0,0,0);
      acc = __builtin_amdgcn_mfma_f32_16x16x32_bf16(ah, bl, acc, 0,0,0);
    }
    if (mi < 8){
      const float ba = b_A[mi];
      #pragma unroll
      for (int q = 0; q < 4; ++q){
        const int er = rg*16 + kg*4 + q;
        const float s = san(acc[q] + ba);
        scores[(size_t)(e0 + er)*8 + mi] = s;
        atomicMax(&segmax[(size_t)tIdx[er]*8 + mi], fmap(s));
      }
    }
  }

  #pragma unroll
  for (int rg = 0; rg < 2; ++rg)
    #pragma unroll
    for (int t2 = 0; t2 < 2; ++t2){
      const int n = (wv*2 + t2)*16 + mi;
      f32x4 acc = {0,0,0,0};
      #pragma unroll
      for (int ks = 0; ks < 4; ++ks){
        const int kb = ks*32 + kg*8;
        const int ao = ((ks*4 + kg)*16 + mi)*8;
        const short8 ah = *reinterpret_cast<const short8*>(&AFh[rg*2048 + ao]);
        const short8 al = *reinterpret_cast<const short8*>(&AFl[rg*2048 + ao]);
        const short8 bh = *reinterpret_cast<const short8*>(&wsw[OFF_WEO + n*128 + kb]);
        const short8 bl = *reinterpret_cast<const short8*>(&wsw[OFF_WEO + WT_SZ + n*128 + kb]);
        acc = __builtin_amdgcn_mfma_f32_16x16x32_bf16(ah, bh, acc, 0,0,0);
        acc = __builtin_amdgcn_mfma_f32_16x16x32_bf16(al, bh, acc, 0,0,0);
        acc = __builtin_amdgcn_mfma_f32_16x16x32_bf16(ah, bl, acc, 0,0,0);
      }
      const float be = b_Eo[n];
      #pragma unroll
      for (int q = 0; q < 4; ++q)
        oute[(size_t)(e0 + rg*16 + kg*4 + q)*128 + n] = san(acc[q] + be);
    }
}

__global__ __launch_bounds__(256) void seg_sum_v20(const float* __restrict__ scores,
    const int* __restrict__ eidx, const unsigned* __restrict__ segmax,
    float* __restrict__ segsum)
{
  int i = blockIdx.x*256 + threadIdx.x;
  if (i >= N_EDGES*8) return;
  int e = i >> 3, h = i & 7;
  int t = eidx[N_EDGES + e];
  float m = funmap(segmax[(size_t)t*8 + h]);
  atomicAdd(&segsum[(size_t)t*8 + h], expf(scores[i] - m));
}

__global__ __launch_bounds__(256) void messages_mfma_v20(
    const float* __restrict__ ea, const int* __restrict__ eidx,
    const float* __restrict__ Vn, const float* __restrict__ b_Ev,
    const short* __restrict__ wsw,
    const float* __restrict__ scores, const unsigned* __restrict__ segmax,
    const float* __restrict__ segsum, float* __restrict__ agg)
{
  __shared__ __align__(16) short Eh[2][2048], El[2][2048];
  __shared__ int sIdx[32], tIdx[32];

  const int tid = threadIdx.x;
  const int e0  = blockIdx.x * 32;

  if (tid < 32){
    sIdx[tid] = eidx[e0 + tid];
    tIdx[tid] = eidx[N_EDGES + e0 + tid];
  }
  {
    const int r = tid & 15, c = tid >> 4;
    #pragma unroll
    for (int rg = 0; rg < 2; ++rg)
      stage_row(ea + (size_t)(e0 + rg*16 + r)*128 + c*8,
                &Eh[rg][(c*16 + r)*8], &El[rg][(c*16 + r)*8]);
  }
  __syncthreads();

  const int wv = tid >> 6;
  const int mi = (tid & 63) & 15;
  const int kg = (tid & 63) >> 4;

  f32x4 aev[2][2];
  #pragma unroll
  for (int rg = 0; rg < 2; ++rg)
    #pragma unroll
    for (int t = 0; t < 2; ++t) aev[rg][t] = (f32x4){0,0,0,0};

  #pragma unroll
  for (int ks = 0; ks < 4; ++ks){
    const int ao = ((ks*4 + kg)*16 + mi)*8;
    const int kb = ks*32 + kg*8;
    short8 eh[2], el_[2];
    #pragma unroll
    for (int rg = 0; rg < 2; ++rg){
      eh[rg]  = *reinterpret_cast<const short8*>(&Eh[rg][ao]);
      el_[rg] = *reinterpret_cast<const short8*>(&El[rg][ao]);
    }
    #pragma unroll
    for (int t = 0; t < 2; ++t){
      const int n = (wv*2 + t)*16 + mi;
      const short8 bh = *reinterpret_cast<const short8*>(&wsw[OFF_WEV + n*128 + kb]);
      const short8 bl = *reinterpret_cast<const short8*>(&wsw[OFF_WEV + WT_SZ + n*128 + kb]);
      #pragma unroll
      for (int rg = 0; rg < 2; ++rg){
        aev[rg][t] = __builtin_amdgcn_mfma_f32_16x16x32_bf16(eh[rg], bh, aev[rg][t], 0,0,0);
        aev[rg][t] = __builtin_amdgcn_mfma_f32_16x16x32_bf16(el_[rg], bh, aev[rg][t], 0,0,0);
        aev[rg][t] = __builtin_amdgcn_mfma_f32_16x16x32_bf16(eh[rg], bl, aev[rg][t], 0,0,0);
      }
    }
  }

  #pragma unroll
  for (int rg = 0; rg < 2; ++rg)
    #pragma unroll
    for (int t = 0; t < 2; ++t){
      const int n = (wv*2 + t)*16 + mi;
      const int h = n >> 4;
      const float be = b_Ev[n];
      #pragma unroll
      for (int q = 0; q < 4; ++q){
        const int row = rg*16 + kg*4 + q;
        const size_t e = (size_t)e0 + row;
        const int s = sIdx[row], tg = tIdx[row];
        const float m   = funmap(segmax[(size_t)tg*8 + h]);
        const float dn  = segsum[(size_t)tg*8 + h] + 1e-16f;
        const float a   = expf(scores[e*8 + h] - m) / dn;
        const float msg = san((Vn[(size_t)s*128 + n] + aev[rg][t][q] + be) * a);
        atomicAdd(&agg[(size_t)tg*128 + n], msg);
      }
    }
}

__global__ __launch_bounds__(256) void messages_v14f(
    const float* __restrict__ x, const float* __restrict__ ea,
    const int* __restrict__ eidx,
    const float* __restrict__ W_V,  const float* __restrict__ b_V,
    const float* __restrict__ W_Ev, const float* __restrict__ b_Ev,
    const float* __restrict__ scores, const unsigned* __restrict__ segmax,
    const float* __restrict__ segsum, float* __restrict__ agg)
{
  __shared__ float eaT[128][16], xsT[128][16];
  __shared__ int sIdx[16], tIdx[16];

  const int tid = threadIdx.x;
  const int e0  = blockIdx.x * 16;

  if (tid < 16){
    sIdx[tid] = eidx[e0 + tid];
    tIdx[tid] = eidx[N_EDGES + e0 + tid];
  }
  __syncthreads();

  for (int idx = tid; idx < 16*128; idx += 256){
    int r = idx >> 7, k = idx & 127;
    eaT[k][r] = ea[(size_t)(e0 + r)*128 + k];
    xsT[k][r] = x[(size_t)sIdx[r]*128 + k];
  }
  __syncthreads();

  const int j  = tid & 127;
  const int h8 = (tid >> 7) * 8;

  float av[8], ae[8];
  #pragma unroll
  for (int i=0;i<8;i++){ av[i]=0.f; ae[i]=0.f; }

  for (int k=0;k<128;k++){
    const float wv = W_V[(size_t)k*128 + j];
    const float we = W_Ev[(size_t)k*128 + j];
    const float4 s0 = *reinterpret_cast<const float4*>(&xsT[k][h8]);
    const float4 s1 = *reinterpret_cast<const float4*>(&xsT[k][h8+4]);
    const float4 e0v = *reinterpret_cast<const float4*>(&eaT[k][h8]);
    const float4 e1v = *reinterpret_cast<const float4*>(&eaT[k][h8+4]);
    const float sv[8] = {s0.x,s0.y,s0.z,s0.w,s1.x,s1.y,s1.z,s1.w};
    const float ev[8] = {e0v.x,e0v.y,e0v.z,e0v.w,e1v.x,e1v.y,e1v.z,e1v.w};
    #pragma unroll
    for (int i=0;i<8;i++){
      av[i] = fmaf(sv[i], wv, av[i]);
      ae[i] = fmaf(ev[i], we, ae[i]);
    }
  }

  const float bv = b_V[j], be = b_Ev[j];
  const int h = j >> 4;
  #pragma unroll
  for (int i=0;i<8;i++){
    const int el = h8 + i;
    const size_t e = (size_t)e0 + el;
    const int t = tIdx[el];
    const float m   = funmap(segmax[(size_t)t*8 + h]);
    const float d   = segsum[(size_t)t*8 + h] + 1e-16f;
    const float a   = expf(scores[e*8 + h] - m) / d;
    const float msg = san(((av[i] + bv) + (ae[i] + be)) * a);
    atomicAdd(&agg[(size_t)t*128 + j], msg);
  }
}

__global__ __launch_bounds__(256) void oproj_v20(const float* __restrict__ agg,
    const float* __restrict__ W, const float* __restrict__ bias,
    float* __restrict__ outx)
{
  __shared__ float AT[128][32];
  const int tid  = threadIdx.x;
  const int base = blockIdx.x * 32;

  for (int idx = tid; idx < 32*128; idx += 256){
    int r = idx >> 7, k = idx & 127;
    AT[k][r] = agg[(size_t)(base + r)*128 + k];
  }
  __syncthreads();

  const int j  = tid & 127;
  const int rb = (tid >> 7) * 16;
  float acc[16];
  #pragma unroll
  for (int i=0;i<16;i++) acc[i] = 0.f;

  for (int k=0;k<128;k++){
    const float w = W[(size_t)k*128 + j];
    const float4 a0 = *reinterpret_cast<const float4*>(&AT[k][rb]);
    const float4 a1 = *reinterpret_cast<const float4*>(&AT[k][rb+4]);
    const float4 a2 = *reinterpret_cast<const float4*>(&AT[k][rb+8]);
    const float4 a3 = *reinterpret_cast<const float4*>(&AT[k][rb+12]);
    const float avv[16] = {a0.x,a0.y,a0.z,a0.w,a1.x,a1.y,a1.z,a1.w,
                           a2.x,a2.y,a2.z,a2.w,a3.x,a3.y,a3.z,a3.w};
    #pragma unroll
    for (int i=0;i<16;i++) acc[i] = fmaf(avv[i], w, acc[i]);
  }

  const float bj = bias[j];
  #pragma unroll
  for (int i=0;i<16;i++)
    outx[(size_t)(base + rb + i)*128 + j] = san(acc[i] + bj);
}

// ---- tier-0 fallback front (r14-proven)
template<bool PREPPED>
__global__ __launch_bounds__(256) void front_v14f(
    const float* __restrict__ x, const float* __restrict__ ea,
    const int* __restrict__ eidx,
    const float* __restrict__ W_Q, const float* __restrict__ b_Q,
    const float* __restrict__ W_K, const float* __restrict__ b_K,
    const float* __restrict__ W_Ew, const float* __restrict__ b_Ew,
    const float* __restrict__ W_Eb, const float* __restrict__ b_Eb,
    const float* __restrict__ b_A,
    const float* __restrict__ W_Eo, const float* __restrict__ b_Eo,
    const short* __restrict__ wsw,
    float* __restrict__ scores, unsigned* __restrict__ segmax,
    float* __restrict__ oute, int eo_min)
{
  __shared__ __align__(16) short AFh[3][2048];
  __shared__ __align__(16) short AFl[3][2048];
  __shared__ int sIdx[16], tIdx[16];

  const int tid = threadIdx.x;
  const int e0  = blockIdx.x * 16;

  if (tid < 16){
    sIdx[tid] = eidx[e0 + tid];
    tIdx[tid] = eidx[N_EDGES + e0 + tid];
  }
  __syncthreads();

  {
    const int r = tid & 15, c = tid >> 4;
    const int off = (c*16 + r)*8;
    stage_row(x  + (size_t)sIdx[r]*128 + c*8, &AFh[0][off], &AFl[0][off]);
    stage_row(x  + (size_t)tIdx[r]*128 + c*8, &AFh[1][off], &AFl[1][off]);
    stage_row(ea + (size_t)(e0 + r)*128 + c*8, &AFh[2][off], &AFl[2][off]);
  }
  __syncthreads();

  const int wv = tid >> 6;
  const int mi = (tid & 63) & 15;
  const int kg = (tid & 63) >> 4;

  f32x4 aq[2], ak[2], aw[2], ab[2];
  #pragma unroll
  for (int t = 0; t < 2; ++t){
    aq[t] = (f32x4){0,0,0,0}; ak[t] = (f32x4){0,0,0,0};
    aw[t] = (f32x4){0,0,0,0}; ab[t] = (f32x4){0,0,0,0};
  }

  #pragma unroll
  for (int ks = 0; ks < 4; ++ks){
    const int ao = ((ks*4 + kg)*16 + mi)*8;
    const short8 xh = *reinterpret_cast<const short8*>(&AFh[0][ao]);
    const short8 xl = *reinterpret_cast<const short8*>(&AFl[0][ao]);
    const short8 th = *reinterpret_cast<const short8*>(&AFh[1][ao]);
    const short8 tl = *reinterpret_cast<const short8*>(&AFl[1][ao]);
    const short8 eh = *reinterpret_cast<const short8*>(&AFh[2][ao]);
    const short8 el = *reinterpret_cast<const short8*>(&AFl[2][ao]);
    const int kb = ks*32 + kg*8;

    #pragma unroll
    for (int t = 0; t < 2; ++t){
      const int n = (wv*2 + t)*16 + mi;
      short8 qh, ql, kh, kl, wh, wl, bh, bl;
      if (PREPPED){
        qh = *reinterpret_cast<const short8*>(&wsw[OFF_WQ  + n*128 + kb]);
        ql = *reinterpret_cast<const short8*>(&wsw[OFF_WQ  + WT_SZ + n*128 + kb]);
        kh = *reinterpret_cast<const short8*>(&wsw[OFF_WK  + n*128 + kb]);
        kl = *reinterpret_cast<const short8*>(&wsw[OFF_WK  + WT_SZ + n*128 + kb]);
        wh = *reinterpret_cast<const short8*>(&wsw[OFF_WEW + n*128 + kb]);
        wl = *reinterpret_cast<const short8*>(&wsw[OFF_WEW + WT_SZ + n*128 + kb]);
        bh = *reinterpret_cast<const short8*>(&wsw[OFF_WEB + n*128 + kb]);
        bl = *reinterpret_cast<const short8*>(&wsw[OFF_WEB + WT_SZ + n*128 + kb]);
      } else {
        #pragma unroll
        for (int q = 0; q < 8; ++q){
          short h, l;
          split(W_Q [(size_t)(kb + q)*128 + n], h, l); qh[q] = h; ql[q] = l;
          split(W_K [(size_t)(kb + q)*128 + n], h, l); kh[q] = h; kl[q] = l;
          split(W_Ew[(size_t)(kb + q)*128 + n], h, l); wh[q] = h; wl[q] = l;
          split(W_Eb[(size_t)(kb + q)*128 + n], h, l); bh[q] = h; bl[q] = l;
        }
      }
      aq[t] = __builtin_amdgcn_mfma_f32_16x16x32_bf16(xh, qh, aq[t], 0,0,0);
      ak[t] = __builtin_amdgcn_mfma_f32_16x16x32_bf16(th, kh, ak[t], 0,0,0);
      aw[t] = __builtin_amdgcn_mfma_f32_16x16x32_bf16(eh, wh, aw[t], 0,0,0);
      ab[t] = __builtin_amdgcn_mfma_f32_16x16x32_bf16(eh, bh, ab[t], 0,0,0);
      aq[t] = __builtin_amdgcn_mfma_f32_16x16x32_bf16(xl, qh, aq[t], 0,0,0);
      ak[t] = __builtin_amdgcn_mfma_f32_16x16x32_bf16(tl, kh, ak[t], 0,0,0);
      aw[t] = __builtin_amdgcn_mfma_f32_16x16x32_bf16(el, wh, aw[t], 0,0,0);
      ab[t] = __builtin_amdgcn_mfma_f32_16x16x32_bf16(el, bh, ab[t], 0,0,0);
      aq[t] = __builtin_amdgcn_mfma_f32_16x16x32_bf16(xh, ql, aq[t], 0,0,0);
      ak[t] = __builtin_amdgcn_mfma_f32_16x16x32_bf16(th, kl, ak[t], 0,0,0);
      aw[t] = __builtin_amdgcn_mfma_f32_16x16x32_bf16(eh, wl, aw[t], 0,0,0);
      ab[t] = __builtin_amdgcn_mfma_f32_16x16x32_bf16(eh, bl, ab[t], 0,0,0);
    }
  }

  short afh[2][4], afl[2][4];
  #pragma unroll
  for (int t = 0; t < 2; ++t){
    const int n = (wv*2 + t)*16 + mi;
    const float bqk = b_Q[n] + b_K[n];
    const float bw  = b_Ew[n];
    const float bb  = b_Eb[n];
    #pragma unroll
    for (int q = 0; q < 4; ++q){
      const float qk = aq[t][q] + ak[t][q] + bqk;
      const float ew = aw[t][q] + bw;
      const float eb = ab[t][q] + bb;
      const float pre = qk * ew;
      const float ssv = pre > 0.f ?  sqrtf( pre + 1e-8f)
                      : (pre < 0.f ? -sqrtf(-pre + 1e-8f) : 0.f);
      const float af = fmaxf(ssv + eb, 0.f);
      short hh, ll; split(af, hh, ll);
      afh[t][q] = hh; afl[t][q] = ll;
    }
  }
  __syncthreads();

  #pragma unroll
  for (int t = 0; t < 2; ++t){
    const int c  = (wv*2 + t)*2 + (mi >> 3);
    const int k7 = mi & 7;
    #pragma unroll
    for (int q = 0; q < 4; ++q){
      const int idx = (c*16 + kg*4 + q)*8 + k7;
      AFh[0][idx] = afh[t][q];
      AFl[0][idx] = afl[t][q];
    }
  }
  __syncthreads();

  if (PREPPED && wv == 0){
    f32x4 acc = {0,0,0,0};
    #pragma unroll
    for (int ks = 0; ks < 4; ++ks){
      const int kb = ks*32 + kg*8;
      const int ao = ((ks*4 + kg)*16 + mi)*8;
      const short8 ah = *reinterpret_cast<const short8*>(&AFh[0][ao]);
      const short8 al = *reinterpret_cast<const short8*>(&AFl[0][ao]);
      const short8 bh = *reinterpret_cast<const short8*>(&wsw[OFF_WA + mi*128 + kb]);
      const short8 bl = *reinterpret_cast<const short8*>(&wsw[OFF_WA + 2048 + mi*128 + kb]);
      acc = __builtin_amdgcn_mfma_f32_16x16x32_bf16(ah, bh, acc, 0,0,0);
      acc = __builtin_amdgcn_mfma_f32_16x16x32_bf16(al, bh, acc, 0,0,0);
      acc = __builtin_amdgcn_mfma_f32_16x16x32_bf16(ah, bl, acc, 0,0,0);
    }
    if (mi < 8){
      const float ba = b_A[mi];
      #pragma unroll
      for (int q = 0; q < 4; ++q){
        const int er = kg*4 + q;
        const float s = san(acc[q] + ba);
        scores[(size_t)(e0 + er)*8 + mi] = s;
        atomicMax(&segmax[(size_t)tIdx[er]*8 + mi], fmap(s));
      }
    }
  }

  if (e0 >= eo_min){
    #pragma unroll
    for (int t2 = 0; t2 < 2; ++t2){
      const int n = (wv*2 + t2)*16 + mi;
      f32x4 acc = {0,0,0,0};
      #pragma unroll
      for (int ks = 0; ks < 4; ++ks){
        const int kb = ks*32 + kg*8;
        const int ao = ((ks*4 + kg)*16 + mi)*8;
        const short8 ah = *reinterpret_cast<const short8*>(&AFh[0][ao]);
        const short8 al = *reinterpret_cast<const short8*>(&AFl[0][ao]);
        short8 bh, bl;
        if (PREPPED){
          bh = *reinterpret_cast<const short8*>(&wsw[OFF_WEO + n*128 + kb]);
          bl = *reinterpret_cast<const short8*>(&wsw[OFF_WEO + WT_SZ + n*128 + kb]);
        } else {
          #pragma unroll
          for (int q = 0; q < 8; ++q){
            short h, l; split(W_Eo[(size_t)(kb + q)*128 + n], h, l); bh[q] = h; bl[q] = l;
          }
        }
        acc = __builtin_amdgcn_mfma_f32_16x16x32_bf16(ah, bh, acc, 0,0,0);
        acc = __builtin_amdgcn_mfma_f32_16x16x32_bf16(al, bh, acc, 0,0,0);
        acc = __builtin_amdgcn_mfma_f32_16x16x32_bf16(ah, bl, acc, 0,0,0);
      }
      const float be = b_Eo[n];
      #pragma unroll
      for (int q = 0; q < 4; ++q)
        oute[(size_t)(e0 + kg*4 + q)*128 + n] = san(acc[q] + be);
    }
  }
}

extern "C" void kernel_launch(void* const* d_in, const int* in_sizes, int n_in,
                              void* d_out, int out_size, void* d_ws, size_t ws_size,
                              hipStream_t stream)
{
  (void)in_sizes; (void)n_in; (void)out_size;
  const float* x    = (const float*)d_in[0];
  const float* ea   = (const float*)d_in[1];
  const int*   eidx = (const int*)d_in[2];
  const float* W_Q  = (const float*)d_in[4];  const float* b_Q  = (const float*)d_in[5];
  const float* W_K  = (const float*)d_in[6];  const float* b_K  = (const float*)d_in[7];
  const float* W_V  = (const float*)d_in[8];  const float* b_V  = (const float*)d_in[9];
  const float* W_Ew = (const float*)d_in[10]; const float* b_Ew = (const float*)d_in[11];
  const float* W_Eb = (const float*)d_in[12]; const float* b_Eb = (const float*)d_in[13];
  const float* W_Ev = (const float*)d_in[14]; const float* b_Ev = (const float*)d_in[15];
  const float* W_O  = (const float*)d_in[16]; const float* b_O  = (const float*)d_in[17];
  const float* W_Eo = (const float*)d_in[18]; const float* b_Eo = (const float*)d_in[19];
  const float* W_A  = (const float*)d_in[20]; const float* b_A  = (const float*)d_in[21];

  float* out_x = (float*)d_out;
  float* oute  = out_x + OUT_E_ELEM;

  const size_t SZ_NODEF  = (size_t)N_NODES*128*4;                    // 51.2 MB
  const size_t NEED_QK    = 2*SZ_NODEF + WSW_BYTES;                  // ~102.9 MB
  const size_t NEED_FULL  = 3*SZ_NODEF + WSW_BYTES;                  // ~154.1 MB
  const size_t NEED_FUSED = NEED_FULL + SEG_B;                       // ~157.3 MB

  dim3 blk(256);

  if (ws_size >= NEED_FUSED){
    // ================= tier 3: fully fused =================
    char*  ws  = (char*)d_ws;
    float* Qn  = (float*)ws;
    float* Kn  = (float*)(ws + SZ_NODEF);
    float* Vn  = (float*)(ws + 2*SZ_NODEF);
    short* wsw = (short*)(ws + 3*SZ_NODEF);
    float* den = (float*)(ws + NEED_FULL);
    float* agg = out_x;          // in-place with oproj_div (stages own rows)

    hipMemsetAsync((void*)agg, 0, AGG_BYTES, stream);
    hipMemsetAsync((void*)den, 0, SEG_B, stream);

    prep_v20<<<dim3(912), dim3(128), 0, stream>>>(W_Q, W_K, W_Ew, W_Eb, W_Eo, W_V, W_Ev, W_A, wsw);

    nodeproj_v20<<<dim3(N_NODES/32), blk, 0, stream>>>(x, wsw, b_Q, b_K, b_V,
        Qn, Kn, Vn, 1);

    front_fused_v20<<<dim3(N_EDGES/32), blk, 0, stream>>>(ea, eidx, Qn, Kn, Vn,
        b_Ew, b_Eb, b_A, b_Eo, b_Ev, wsw, den, agg, oute);

    oproj_div_v20<<<dim3(N_NODES/32), blk, 0, stream>>>(agg, den, W_O, b_O, out_x);

  } else {
    // ================= tiers 0/1/2: r19-proven chain =================
    float*    scores = (float*)d_out;
    unsigned* segmax = (unsigned*)((char*)d_out + SCORES_B);
    float*    segsum = (float*)((char*)d_out + SCORES_B + SEG_B);
    const int tier = (ws_size >= NEED_FULL) ? 2 : (ws_size >= NEED_QK) ? 1 : 0;

    hipMemsetAsync((void*)segmax, 0, 2*SEG_B, stream);

    if (tier >= 1){
      char*  ws  = (char*)d_ws;
      float* Qn  = (float*)ws;
      float* Kn  = (float*)(ws + SZ_NODEF);
      float* Vn  = (tier == 2) ? (float*)(ws + 2*SZ_NODEF) : nullptr;
      short* wsw = (short*)(ws + ((tier == 2) ? 3 : 2)*SZ_NODEF);
      float* agg = Qn;

      prep_v20<<<dim3(912), dim3(128), 0, stream>>>(W_Q, W_K, W_Ew, W_Eb, W_Eo, W_V, W_Ev, W_A, wsw);

      nodeproj_v20<<<dim3(N_NODES/32), blk, 0, stream>>>(x, wsw, b_Q, b_K, b_V,
          Qn, Kn, Vn, tier == 2 ? 1 : 0);

      front_qk_v19f<<<dim3(N_EDGES/32), blk, 0, stream>>>(ea, eidx, Qn, Kn,
          b_Ew, b_Eb, b_A, b_Eo, wsw, scores, segmax, oute, 1);

      hipMemsetAsync((void*)agg, 0, AGG_BYTES, stream);

      seg_sum_v20<<<dim3((N_EDGES*8 + 255)/256), blk, 0, stream>>>(scores, eidx, segmax, segsum);

      if (tier == 2)
        messages_mfma_v20<<<dim3(N_EDGES/32), blk, 0, stream>>>(ea, eidx, Vn, b_Ev,
            wsw, scores, segmax, segsum, agg);
      else
        messages_v14f<<<dim3(N_EDGES/16), blk, 0, stream>>>(x, ea, eidx,
            W_V, b_V, W_Ev, b_Ev, scores, segmax, segsum, agg);

      oproj_v20<<<dim3(N_NODES/32), blk, 0, stream>>>(agg, W_O, b_O, out_x);

    } else {
      short* wsw = (short*)((char*)d_out + WSW_OFF);
      float* agg = oute;

      hipMemsetAsync((void*)agg, 0, AGG_BYTES, stream);

      prep_v20<<<dim3(912), dim3(128), 0, stream>>>(W_Q, W_K, W_Ew, W_Eb, W_Eo, W_V, W_Ev, W_A, wsw);

      front_v14f<true><<<dim3(N_EDGES/16), blk, 0, stream>>>(x, ea, eidx,
          W_Q, b_Q, W_K, b_K, W_Ew, b_Ew, W_Eb, b_Eb, b_A, W_Eo, b_Eo, wsw,
          scores, segmax, oute, EO_MIN);

      seg_sum_v20<<<dim3((N_EDGES*8 + 255)/256), blk, 0, stream>>>(scores, eidx, segmax, segsum);

      messages_v14f<<<dim3(N_EDGES/16), blk, 0, stream>>>(x, ea, eidx,
          W_V, b_V, W_Ev, b_Ev, scores, segmax, segsum, agg);

      oproj_v20<<<dim3(N_NODES/32), blk, 0, stream>>>(agg, W_O, b_O, out_x);

      front_v14f<false><<<dim3(EO_MIN/16), blk, 0, stream>>>(x, ea, eidx,
          W_Q, b_Q, W_K, b_K, W_Ew, b_Ew, W_Eb, b_Eb, b_A, W_Eo, b_Eo, nullptr,
          nullptr, nullptr, oute, 0);
    }
  }
}